// Round 1
// baseline (18771.484 us; speedup 1.0000x reference)
//
#include <hip/hip_runtime.h>
#include <math.h>

// ---------------------------------------------------------------------------
// DiacritizerD3: full fp32 pipeline.
// B=32, TS=16, TW=16, SENT_H=256 (DIN=512), WORD_H=512 (DQ=DEC_H=1024),
// CDIM=32, WDIM=300, DEC_IN=1544.
// ---------------------------------------------------------------------------

__device__ __forceinline__ float sigf(float x) { return 1.0f / (1.0f + expf(-x)); }

#define FMA16(a, b, acc)                                                           \
  acc[0][0] += a.x * b.x; acc[0][1] += a.x * b.y; acc[0][2] += a.x * b.z; acc[0][3] += a.x * b.w; \
  acc[1][0] += a.y * b.x; acc[1][1] += a.y * b.y; acc[1][2] += a.y * b.z; acc[1][3] += a.y * b.w; \
  acc[2][0] += a.z * b.x; acc[2][1] += a.z * b.y; acc[2][2] += a.z * b.z; acc[2][3] += a.z * b.w; \
  acc[3][0] += a.w * b.x; acc[3][1] += a.w * b.y; acc[3][2] += a.w * b.z; acc[3][3] += a.w * b.w;

// ---------------- transpose (+optional unit-major reorder of source rows) ----
// out[c*R + r] = in[gsrc(r)*C + c];  gsrc(r) = (r&3)*H + (r>>2) if H>0 else r
__global__ __launch_bounds__(256) void transpose_k(const float* __restrict__ in,
                                                   float* __restrict__ out,
                                                   int R, int C, int H) {
  __shared__ float tile[32][33];
  int r0 = blockIdx.x * 32, c0 = blockIdx.y * 32;
  int tx = threadIdx.x & 31, ty = threadIdx.x >> 5;
  for (int yy = ty; yy < 32; yy += 8) {
    int r = r0 + yy, c = c0 + tx;
    float v = 0.f;
    if (r < R && c < C) {
      int gs = H ? ((r & 3) * H + (r >> 2)) : r;
      v = in[(long)gs * C + c];
    }
    tile[yy][tx] = v;
  }
  __syncthreads();
  for (int yy = ty; yy < 32; yy += 8) {
    int c = c0 + yy, r = r0 + tx;
    if (r < R && c < C) out[(long)c * R + r] = tile[tx][yy];
  }
}

// ---------------- embedding lookup ------------------------------------------
__global__ void embed_k(const int* __restrict__ sents, const float* __restrict__ word_embs,
                        float* __restrict__ wembs) {
  int idx = blockIdx.x * 256 + threadIdx.x;
  if (idx >= 512 * 300) return;
  int r = idx / 300, k = idx - r * 300;
  wembs[idx] = word_embs[(long)sents[r] * 300 + k];
}

// ---------------- char-encoder input build ----------------------------------
// charin[n][c][k]: k<32 -> char_table[words[n][c]][k];
// k>=32 -> sent_enc[n][k-32] * (words[n][c] != 0)
__global__ void charin_k(const int* __restrict__ words, const float* __restrict__ char_table,
                         const float* __restrict__ sent_enc, float* __restrict__ charin) {
  int idx = blockIdx.x * 256 + threadIdx.x;
  if (idx >= 512 * 16 * 544) return;
  int k = idx % 544;
  int rc = idx / 544;
  int c = rc & 15, n = rc >> 4;
  int w = words[n * 16 + c];
  float v;
  if (k < 32) v = char_table[w * 32 + k];
  else v = (w != 0) ? sent_enc[n * 512 + (k - 32)] : 0.f;
  charin[idx] = v;
}

// ---------------- labels -> final[:,1536:1544] ------------------------------
__global__ void labels_k(const int* __restrict__ labels, float* __restrict__ finalb) {
  int idx = blockIdx.x * 256 + threadIdx.x;
  if (idx >= 8192 * 8) return;
  int r = idx >> 3, l = idx & 7;
  finalb[(long)r * 1544 + 1536 + l] = (float)labels[idx];
}

// ---------------- generic fp32 GEMM: C = A * B^T (+bias) --------------------
// A: row-major, row index either m (AMODE 0) or decoder-chunk remap (AMODE 1):
//   arow = (m&31)*256 + at0 + (m>>5)   (b-fast, 32-step chunk)
// B: [N][K] row-major; optional unit-major reorder: gsrc = (n&3)*BH + (n>>2)
template <int AMODE, int BH, int HASBIAS>
__global__ __launch_bounds__(256) void gemm_k(const float* __restrict__ A, int lda, int at0,
                                              const float* __restrict__ Bw,
                                              const float* __restrict__ bias,
                                              float* __restrict__ C, int ldc,
                                              int M, int N, int K) {
  __shared__ float As[32][64];
  __shared__ float Bs[32][64];
  int tid = threadIdx.x;
  int m0 = blockIdx.x * 64, n0 = blockIdx.y * 64;
  int tn = tid & 15, tm = tid >> 4;
  int lrow = tid >> 2, lk = (tid & 3) * 8;
  float acc[4][4] = {};
  int am = m0 + lrow;
  long arow = (AMODE == 1) ? ((long)(am & 31) * 256 + at0 + (am >> 5)) : (long)am;
  const float* aptr = A + arow * (long)lda;
  bool mok = am < M;
  int bn = n0 + lrow;
  int gsrc = (BH > 0) ? ((bn & 3) * BH + (bn >> 2)) : bn;
  const float* bptr = Bw + (long)gsrc * (long)K;
  bool nok = bn < N;

  for (int k0 = 0; k0 < K; k0 += 32) {
    int kb = k0 + lk;
    if (kb + 8 <= K) {
      if (mok) {
        float4 v0 = *(const float4*)(aptr + kb);
        float4 v1 = *(const float4*)(aptr + kb + 4);
        As[lk + 0][lrow] = v0.x; As[lk + 1][lrow] = v0.y; As[lk + 2][lrow] = v0.z; As[lk + 3][lrow] = v0.w;
        As[lk + 4][lrow] = v1.x; As[lk + 5][lrow] = v1.y; As[lk + 6][lrow] = v1.z; As[lk + 7][lrow] = v1.w;
      } else {
#pragma unroll
        for (int i = 0; i < 8; i++) As[lk + i][lrow] = 0.f;
      }
      if (nok) {
        float4 v0 = *(const float4*)(bptr + kb);
        float4 v1 = *(const float4*)(bptr + kb + 4);
        Bs[lk + 0][lrow] = v0.x; Bs[lk + 1][lrow] = v0.y; Bs[lk + 2][lrow] = v0.z; Bs[lk + 3][lrow] = v0.w;
        Bs[lk + 4][lrow] = v1.x; Bs[lk + 5][lrow] = v1.y; Bs[lk + 6][lrow] = v1.z; Bs[lk + 7][lrow] = v1.w;
      } else {
#pragma unroll
        for (int i = 0; i < 8; i++) Bs[lk + i][lrow] = 0.f;
      }
    } else {
#pragma unroll
      for (int i = 0; i < 8; i++) {
        int k = kb + i;
        As[lk + i][lrow] = (mok && k < K) ? aptr[k] : 0.f;
        Bs[lk + i][lrow] = (nok && k < K) ? bptr[k] : 0.f;
      }
    }
    __syncthreads();
#pragma unroll
    for (int kk = 0; kk < 32; kk++) {
      float4 a = *(const float4*)&As[kk][tm * 4];
      float4 b = *(const float4*)&Bs[kk][tn * 4];
      FMA16(a, b, acc)
    }
    __syncthreads();
  }
#pragma unroll
  for (int i = 0; i < 4; i++) {
    int m = m0 + tm * 4 + i;
    if (m >= M) continue;
#pragma unroll
    for (int j = 0; j < 4; j++) {
      int n = n0 + tn * 4 + j;
      if (n >= N) continue;
      float v = acc[i][j];
      if (HASBIAS) {
        int gs = (BH > 0) ? ((n & 3) * BH + (n >> 2)) : n;
        v += bias[gs];
      }
      C[(long)m * ldc + n] = v;
    }
  }
}

// ---------------- sentence recurrent (persistent per (batch,dir) block) -----
// pre: [512 rows=(n*16+t)][2048 = dir*1024+gates] (bias already included)
// WhT: [2][256][1024];  out: [n][t][dir*256 + j], row n stride 16*512
__global__ __launch_bounds__(256) void sent_rec_k(const float* __restrict__ pre,
                                                  const float* __restrict__ WhT,
                                                  float* __restrict__ out) {
  int blk = blockIdx.x;
  int n = blk & 31, dir = blk >> 5;
  int tid = threadIdx.x;
  __shared__ float hls[256];
  __shared__ float gls[1024];
  float c = 0.f;
  hls[tid] = 0.f;
  __syncthreads();
  const float* whbase = WhT + (long)dir * 256 * 1024;
  int g4 = tid * 4;
  for (int s = 0; s < 16; s++) {
    int t = dir ? (15 - s) : s;
    const float* prow = pre + (long)(n * 16 + t) * 2048 + dir * 1024;
    float ax = 0.f, ay = 0.f, az = 0.f, aw = 0.f;
#pragma unroll 4
    for (int k = 0; k < 256; k++) {
      float hk = hls[k];
      float4 w = *(const float4*)(whbase + (long)k * 1024 + g4);
      ax += hk * w.x; ay += hk * w.y; az += hk * w.z; aw += hk * w.w;
    }
    float4 p = *(const float4*)(prow + g4);
    gls[g4 + 0] = ax + p.x; gls[g4 + 1] = ay + p.y;
    gls[g4 + 2] = az + p.z; gls[g4 + 3] = aw + p.w;
    __syncthreads();
    float gi = gls[tid], gf = gls[256 + tid], gg = gls[512 + tid], go = gls[768 + tid];
    c = sigf(gf) * c + sigf(gi) * tanhf(gg);
    float h = sigf(go) * tanhf(c);
    __syncthreads();
    hls[tid] = h;
    out[(long)n * 8192 + (long)t * 512 + dir * 256 + tid] = h;
    __syncthreads();
  }
}

// ---------------- char-encoder fused step (GEMM + LSTM cell) ----------------
// One step for both directions. N space: [0,4096) = dir*2048 + unit*4 + gate.
// A row m (512 rows): k<K1 -> x (time-selected base per dir), else h_in.
// Epilogue: per-thread columns are exactly one unit's 4 gates -> fused cell.
__global__ __launch_bounds__(256) void char_step_k(
    const float* __restrict__ xF, const float* __restrict__ xB, int xstride, int K1,
    const float* __restrict__ Wx, const float* __restrict__ Wh,
    const float* __restrict__ bias,
    const float* __restrict__ h_in, float* __restrict__ h_out, float* __restrict__ c_st,
    float* __restrict__ outF, float* __restrict__ outB, int out_rstride) {
  __shared__ float As[32][64];
  __shared__ float Bs[32][64];
  int tid = threadIdx.x;
  int m0 = blockIdx.x * 64;
  int n0 = blockIdx.y * 64;
  int dir = n0 >> 11;
  int nn0 = n0 & 2047;
  const float* xb = dir ? xB : xF;
  int tn = tid & 15, tm = tid >> 4;
  int lrow = tid >> 2, lk = (tid & 3) * 8;
  float acc[4][4] = {};
  int am = m0 + lrow;
  const float* xrow = xb + (long)am * xstride;
  const float* hrow = h_in + (long)dir * 262144 + (long)am * 512;
  int nb = nn0 + lrow;
  int ub = nb >> 2, gb = nb & 3;
  const float* wxrow = Wx + ((long)dir * 2048 + gb * 512 + ub) * (long)K1;
  const float* whrow = Wh + ((long)dir * 2048 + gb * 512 + ub) * 512L;
  int K = K1 + 512;
  for (int k0 = 0; k0 < K; k0 += 32) {
    const float* ap;
    const float* bp;
    if (k0 < K1) { ap = xrow + k0 + lk; bp = wxrow + k0 + lk; }
    else         { ap = hrow + (k0 - K1) + lk; bp = whrow + (k0 - K1) + lk; }
    float4 a0 = *(const float4*)ap;
    float4 a1 = *(const float4*)(ap + 4);
    float4 b0 = *(const float4*)bp;
    float4 b1 = *(const float4*)(bp + 4);
    As[lk + 0][lrow] = a0.x; As[lk + 1][lrow] = a0.y; As[lk + 2][lrow] = a0.z; As[lk + 3][lrow] = a0.w;
    As[lk + 4][lrow] = a1.x; As[lk + 5][lrow] = a1.y; As[lk + 6][lrow] = a1.z; As[lk + 7][lrow] = a1.w;
    Bs[lk + 0][lrow] = b0.x; Bs[lk + 1][lrow] = b0.y; Bs[lk + 2][lrow] = b0.z; Bs[lk + 3][lrow] = b0.w;
    Bs[lk + 4][lrow] = b1.x; Bs[lk + 5][lrow] = b1.y; Bs[lk + 6][lrow] = b1.z; Bs[lk + 7][lrow] = b1.w;
    __syncthreads();
#pragma unroll
    for (int kk = 0; kk < 32; kk++) {
      float4 a = *(const float4*)&As[kk][tm * 4];
      float4 b = *(const float4*)&Bs[kk][tn * 4];
      FMA16(a, b, acc)
    }
    __syncthreads();
  }
  // fused cell: this thread's 4 columns = unit u's gates (i,f,g,o)
  int u = (nn0 >> 2) + tn;
  float bi_ = bias[dir * 2048 + u];
  float bf_ = bias[dir * 2048 + 512 + u];
  float bg_ = bias[dir * 2048 + 1024 + u];
  float bo_ = bias[dir * 2048 + 1536 + u];
  float* ob = dir ? outB : outF;
#pragma unroll
  for (int i = 0; i < 4; i++) {
    int m = m0 + tm * 4 + i;
    float gi_ = acc[i][0] + bi_;
    float gf_ = acc[i][1] + bf_;
    float gg_ = acc[i][2] + bg_;
    float go_ = acc[i][3] + bo_;
    long si = (long)dir * 262144 + (long)m * 512 + u;
    float c = sigf(gf_) * c_st[si] + sigf(gi_) * tanhf(gg_);
    float h = sigf(go_) * tanhf(c);
    c_st[si] = c;
    h_out[si] = h;
    ob[(long)m * out_rstride + u] = h;
  }
}

// ---------------- decoder step ----------------------------------------------
// grid 256: blk = bs(2) x ublock(128, 8 units each). WhTr: [1024][4096] unit-major.
// pre chunk: [32 tl][32 b][4096] (Wx*x + bias, unit-major). Fused cell + dec_out.
__global__ __launch_bounds__(256) void dec_step_k(const float* __restrict__ WhTr,
                                                  const float* __restrict__ pre,
                                                  const float* __restrict__ h_in,
                                                  float* __restrict__ h_out,
                                                  float* __restrict__ c_st,
                                                  float* __restrict__ dec_out,
                                                  int tloc, int tglob) {
  int blk = blockIdx.x;
  int bs = blk & 1, ub = blk >> 1;
  int u0 = ub * 8;
  int n0 = u0 * 4;
  int tid = threadIdx.x;
  int p = tid & 15, bb = tid >> 4;
  int b = bs * 16 + bb;
  __shared__ float hls[16][1024];
  __shared__ float gls[16][32];
  for (int idx = tid; idx < 4096; idx += 256) {
    int bi = idx >> 8, k4 = idx & 255;
    *(float4*)&hls[bi][k4 * 4] = *(const float4*)(h_in + (long)(bs * 16 + bi) * 1024 + k4 * 4);
  }
  __syncthreads();
  int c0 = n0 + 2 * p;
  float a0 = 0.f, a1 = 0.f;
#pragma unroll 8
  for (int k = 0; k < 1024; k++) {
    float2 w = *(const float2*)(WhTr + (long)k * 4096 + c0);
    float h = hls[bb][k];
    a0 += h * w.x;
    a1 += h * w.y;
  }
  const float* pr = pre + ((long)tloc * 32 + b) * 4096;
  a0 += pr[c0];
  a1 += pr[c0 + 1];
  gls[bb][2 * p] = a0;
  gls[bb][2 * p + 1] = a1;
  __syncthreads();
  if (tid < 128) {
    int ul = tid & 7, bi = tid >> 3;
    int bg = bs * 16 + bi;
    float gi = gls[bi][ul * 4 + 0];
    float gf = gls[bi][ul * 4 + 1];
    float gg = gls[bi][ul * 4 + 2];
    float go = gls[bi][ul * 4 + 3];
    int u = u0 + ul;
    long ci = (long)bg * 1024 + u;
    float c = sigf(gf) * c_st[ci] + sigf(gi) * tanhf(gg);
    float h = sigf(go) * tanhf(c);
    c_st[ci] = c;
    h_out[ci] = h;
    dec_out[((long)bg * 256 + tglob) * 1024 + u] = h;
  }
}

// ---------------- attention (block per (b,i)) -------------------------------
__global__ __launch_bounds__(256) void attn_k(const float* __restrict__ sent_enc,
                                              const float* __restrict__ qbuf,
                                              const int* __restrict__ words,
                                              float* __restrict__ attn_out,
                                              float* __restrict__ finalb) {
  int b = blockIdx.x >> 4;
  int i = blockIdx.x & 15;
  int tid = threadIdx.x;
  __shared__ float se[16][512];
  __shared__ float qq[16][512];
  __shared__ float sc[16][16];
  __shared__ int kv[16];
  if (tid < 16) kv[tid] = 0;
  __syncthreads();
  {
    int j = tid >> 4, c = tid & 15;
    if (words[(b * 16 + j) * 16 + c] != 0) atomicOr(&kv[j], 1);
  }
  for (int idx = tid; idx < 16 * 128; idx += 256) {
    int j = idx >> 7, d4 = idx & 127;
    *(float4*)&se[j][d4 * 4] = *(const float4*)(sent_enc + (long)(b * 16 + j) * 512 + d4 * 4);
  }
  for (int idx = tid; idx < 16 * 128; idx += 256) {
    int c = idx >> 7, d4 = idx & 127;
    *(float4*)&qq[c][d4 * 4] = *(const float4*)(qbuf + (long)(b * 256 + i * 16 + c) * 512 + d4 * 4);
  }
  __syncthreads();
  int c = tid >> 4, j = tid & 15;
  {
    float s = 0.f;
#pragma unroll 4
    for (int k = 0; k < 512; k++) s += qq[c][k] * se[j][k];
    bool valid = (kv[j] != 0) && (j != i);
    sc[c][j] = valid ? s : -1e9f;
  }
  __syncthreads();
  float m = -INFINITY;
#pragma unroll
  for (int t = 0; t < 16; t++) m = fmaxf(m, sc[c][t]);
  float den = 0.f;
#pragma unroll
  for (int t = 0; t < 16; t++) den += expf(sc[c][t] - m);
  float a = expf(sc[c][j] - m) / den;
  __syncthreads();
  sc[c][j] = a;
  attn_out[((long)((b * 16 + i) * 16 + c)) * 16 + j] = a;
  __syncthreads();
  {
    int part = tid & 15;
    int cc = tid >> 4;
    for (int d = part * 32; d < part * 32 + 32; d++) {
      float v = 0.f;
#pragma unroll
      for (int jj = 0; jj < 16; jj++) v += sc[cc][jj] * se[jj][d];
      finalb[(long)(b * 256 + i * 16 + cc) * 1544 + d] = v;
    }
  }
}

// ---------------------------------------------------------------------------
extern "C" void kernel_launch(void* const* d_in, const int* in_sizes, int n_in,
                              void* d_out, int out_size, void* d_ws, size_t ws_size,
                              hipStream_t stream) {
  const int* sents = (const int*)d_in[0];
  const int* words = (const int*)d_in[1];
  const int* labels = (const int*)d_in[2];
  const float* word_embs = (const float*)d_in[3];
  const float* char_table = (const float*)d_in[4];
  const float* sent_Wx0 = (const float*)d_in[5];
  const float* sent_Wh0 = (const float*)d_in[6];
  const float* sent_b0 = (const float*)d_in[7];
  const float* sent_Wx1 = (const float*)d_in[8];
  const float* sent_Wh1 = (const float*)d_in[9];
  const float* sent_b1 = (const float*)d_in[10];
  const float* word_Wx0 = (const float*)d_in[11];
  const float* word_Wh0 = (const float*)d_in[12];
  const float* word_b0 = (const float*)d_in[13];
  const float* word_Wx1 = (const float*)d_in[14];
  const float* word_Wh1 = (const float*)d_in[15];
  const float* word_b1 = (const float*)d_in[16];
  const float* attn_Wq = (const float*)d_in[17];
  const float* dec_Wx = (const float*)d_in[18];
  const float* dec_Wh = (const float*)d_in[19];
  const float* dec_b = (const float*)d_in[20];
  const float* cls_W = (const float*)d_in[21];
  const float* cls_b = (const float*)d_in[22];

  float* ws = (float*)d_ws;
  float* wembs   = ws;                   // 153600
  float* preS    = wembs + 153600;       // 1048576
  float* hs0     = preS + 1048576;       // 262144
  float* sentenc = hs0 + 262144;         // 262144
  float* charin  = sentenc + 262144;     // 4456448 (reused: q, dec pre-chunk)
  float* hc0     = charin + 4456448;     // 8388608 (reused: dec_out)
  float* finalb  = hc0 + 8388608;        // 12648448
  float* hchar   = finalb + 12648448;    // 1048576  [2 par][2 dir][512][512]
  float* cchar   = hchar + 1048576;      // 524288
  float* hdec    = cchar + 524288;       // 65536    [2 par][32][1024]
  float* cdec    = hdec + 65536;         // 32768
  float* WhT0    = cdec + 32768;         // 524288   [2][256][1024]
  float* WhT1    = WhT0 + 524288;        // 524288
  float* WqT     = WhT1 + 524288;        // 524288   [512][1024]
  float* WhTr    = WqT + 524288;         // 4194304  [1024][4096]
  float* clsWT   = WhTr + 4194304;       // 15360    [15][1024]

  float* dout = (float*)d_out;
  float* diac = dout;              // 8192 x 15
  float* attnmap = dout + 122880;  // 32 x 16 x 16 x 16

  // ---- weight preprocessing -------------------------------------------------
  transpose_k<<<dim3(32, 8), 256, 0, stream>>>(sent_Wh0, WhT0, 1024, 256, 0);
  transpose_k<<<dim3(32, 8), 256, 0, stream>>>(sent_Wh0 + 262144, WhT0 + 262144, 1024, 256, 0);
  transpose_k<<<dim3(32, 8), 256, 0, stream>>>(sent_Wh1, WhT1, 1024, 256, 0);
  transpose_k<<<dim3(32, 8), 256, 0, stream>>>(sent_Wh1 + 262144, WhT1 + 262144, 1024, 256, 0);
  transpose_k<<<dim3(32, 16), 256, 0, stream>>>(attn_Wq, WqT, 1024, 512, 0);
  transpose_k<<<dim3(128, 32), 256, 0, stream>>>(dec_Wh, WhTr, 4096, 1024, 1024);
  transpose_k<<<dim3(32, 1), 256, 0, stream>>>(cls_W, clsWT, 1024, 15, 0);

  // ---- sentence encoder -----------------------------------------------------
  embed_k<<<600, 256, 0, stream>>>(sents, word_embs, wembs);
  gemm_k<0, 0, 1><<<dim3(8, 32), 256, 0, stream>>>(wembs, 300, 0, sent_Wx0, sent_b0,
                                                   preS, 2048, 512, 2048, 300);
  sent_rec_k<<<64, 256, 0, stream>>>(preS, WhT0, hs0);
  gemm_k<0, 0, 1><<<dim3(8, 32), 256, 0, stream>>>(hs0, 512, 0, sent_Wx1, sent_b1,
                                                   preS, 2048, 512, 2048, 512);
  sent_rec_k<<<64, 256, 0, stream>>>(preS, WhT1, sentenc);

  // ---- char encoder ---------------------------------------------------------
  charin_k<<<17408, 256, 0, stream>>>(words, char_table, sentenc, charin);

  hipMemsetAsync(hchar, 0, (size_t)(1048576 + 524288) * 4, stream);
  for (int s = 0; s < 16; s++) {
    int p = s & 1;
    char_step_k<<<dim3(8, 64), 256, 0, stream>>>(
        charin + s * 544, charin + (15 - s) * 544, 16 * 544, 544,
        word_Wx0, word_Wh0, word_b0,
        hchar + p * 524288, hchar + (p ^ 1) * 524288, cchar,
        hc0 + s * 1024, hc0 + (15 - s) * 1024 + 512, 16 * 1024);
  }
  hipMemsetAsync(hchar, 0, (size_t)(1048576 + 524288) * 4, stream);
  for (int s = 0; s < 16; s++) {
    int p = s & 1;
    char_step_k<<<dim3(8, 64), 256, 0, stream>>>(
        hc0 + s * 1024, hc0 + (15 - s) * 1024, 16 * 1024, 1024,
        word_Wx1, word_Wh1, word_b1,
        hchar + p * 524288, hchar + (p ^ 1) * 524288, cchar,
        finalb + s * 1544 + 512, finalb + (15 - s) * 1544 + 1024, 16 * 1544);
  }

  // ---- attention ------------------------------------------------------------
  // q = char_enc (inside finalb cols 512..1536) @ Wq  -> charin (reused as q)
  gemm_k<0, 0, 0><<<dim3(128, 8), 256, 0, stream>>>(finalb + 512, 1544, 0, WqT, nullptr,
                                                    charin, 512, 8192, 512, 1024);
  attn_k<<<512, 256, 0, stream>>>(sentenc, charin, words, attnmap, finalb);
  labels_k<<<256, 256, 0, stream>>>(labels, finalb);

  // ---- decoder --------------------------------------------------------------
  hipMemsetAsync(hdec, 0, (size_t)(65536 + 32768) * 4, stream);
  for (int ch = 0; ch < 8; ch++) {
    // pre chunk: [32 tl][32 b][4096] = final(row b*256+t) @ dec_Wx^T + dec_b (unit-major)
    gemm_k<1, 1024, 1><<<dim3(16, 64), 256, 0, stream>>>(finalb, 1544, ch * 32, dec_Wx, dec_b,
                                                         charin, 4096, 1024, 4096, 1544);
    for (int sl = 0; sl < 32; sl++) {
      int t = ch * 32 + sl;
      dec_step_k<<<256, 256, 0, stream>>>(WhTr, charin,
                                          hdec + (t & 1) * 32768, hdec + ((t & 1) ^ 1) * 32768,
                                          cdec, hc0 /* dec_out */, sl, t);
    }
  }

  // ---- classifier -----------------------------------------------------------
  gemm_k<0, 0, 1><<<dim3(128, 1), 256, 0, stream>>>(hc0, 1024, 0, clsWT, cls_b,
                                                    diac, 15, 8192, 15, 1024);
}

// Round 2
// 15808.542 us; speedup vs baseline: 1.1874x; 1.1874x over previous
//
#include <hip/hip_runtime.h>
#include <math.h>

// ---------------------------------------------------------------------------
// DiacritizerD3: split-bf16 MFMA pipeline.
// B=32, TS=16, TW=16, SENT_H=256 (DIN=512), WORD_H=512 (DQ=DEC_H=1024),
// CDIM=32, WDIM=300, DEC_IN=1544.
// ---------------------------------------------------------------------------

typedef __attribute__((ext_vector_type(8))) __bf16 bf16x8;
typedef __attribute__((ext_vector_type(4))) float f32x4;

__device__ __forceinline__ float sigf(float x) { return 1.0f / (1.0f + expf(-x)); }

__device__ __forceinline__ unsigned short bf16rn(float x) {
  unsigned u = __float_as_uint(x);
  return (unsigned short)((u + 0x7fffu + ((u >> 16) & 1u)) >> 16);
}
__device__ __forceinline__ void splitf(float x, unsigned short& h, unsigned short& l) {
  h = bf16rn(x);
  float fh = __uint_as_float((unsigned)h << 16);
  l = bf16rn(x - fh);
}

#define FMA16(a, b, acc)                                                           \
  acc[0][0] += a.x * b.x; acc[0][1] += a.x * b.y; acc[0][2] += a.x * b.z; acc[0][3] += a.x * b.w; \
  acc[1][0] += a.y * b.x; acc[1][1] += a.y * b.y; acc[1][2] += a.y * b.z; acc[1][3] += a.y * b.w; \
  acc[2][0] += a.z * b.x; acc[2][1] += a.z * b.y; acc[2][2] += a.z * b.z; acc[2][3] += a.z * b.w; \
  acc[3][0] += a.w * b.x; acc[3][1] += a.w * b.y; acc[3][2] += a.w * b.z; acc[3][3] += a.w * b.w;

// ---------------- transpose (+optional unit-major reorder of source rows) ----
__global__ __launch_bounds__(256) void transpose_k(const float* __restrict__ in,
                                                   float* __restrict__ out,
                                                   int R, int C, int H) {
  __shared__ float tile[32][33];
  int r0 = blockIdx.x * 32, c0 = blockIdx.y * 32;
  int tx = threadIdx.x & 31, ty = threadIdx.x >> 5;
  for (int yy = ty; yy < 32; yy += 8) {
    int r = r0 + yy, c = c0 + tx;
    float v = 0.f;
    if (r < R && c < C) {
      int gs = H ? ((r & 3) * H + (r >> 2)) : r;
      v = in[(long)gs * C + c];
    }
    tile[yy][tx] = v;
  }
  __syncthreads();
  for (int yy = ty; yy < 32; yy += 8) {
    int c = c0 + yy, r = r0 + tx;
    if (r < R && c < C) out[(long)c * R + r] = tile[tx][yy];
  }
}

// ---------------- embedding lookup ------------------------------------------
__global__ void embed_k(const int* __restrict__ sents, const float* __restrict__ word_embs,
                        float* __restrict__ wembs) {
  int idx = blockIdx.x * 256 + threadIdx.x;
  if (idx >= 512 * 300) return;
  int r = idx / 300, k = idx - r * 300;
  wembs[idx] = word_embs[(long)sents[r] * 300 + k];
}

// ---------------- char-encoder input build ----------------------------------
__global__ void charin_k(const int* __restrict__ words, const float* __restrict__ char_table,
                         const float* __restrict__ sent_enc, float* __restrict__ charin) {
  int idx = blockIdx.x * 256 + threadIdx.x;
  if (idx >= 512 * 16 * 544) return;
  int k = idx % 544;
  int rc = idx / 544;
  int c = rc & 15, n = rc >> 4;
  int w = words[n * 16 + c];
  float v;
  if (k < 32) v = char_table[w * 32 + k];
  else v = (w != 0) ? sent_enc[n * 512 + (k - 32)] : 0.f;
  charin[idx] = v;
}

// ---------------- labels -> final[:,1536:1544] ------------------------------
__global__ void labels_k(const int* __restrict__ labels, float* __restrict__ finalb) {
  int idx = blockIdx.x * 256 + threadIdx.x;
  if (idx >= 8192 * 8) return;
  int r = idx >> 3, l = idx & 7;
  finalb[(long)r * 1544 + 1536 + l] = (float)labels[idx];
}

// ---------------- fp32 fallback GEMM (sentence Wx, classifier) --------------
template <int AMODE, int BH, int HASBIAS>
__global__ __launch_bounds__(256) void gemm_k(const float* __restrict__ A, int lda, int at0,
                                              const float* __restrict__ Bw,
                                              const float* __restrict__ bias,
                                              float* __restrict__ C, int ldc,
                                              int M, int N, int K) {
  __shared__ float As[32][64];
  __shared__ float Bs[32][64];
  int tid = threadIdx.x;
  int m0 = blockIdx.x * 64, n0 = blockIdx.y * 64;
  int tn = tid & 15, tm = tid >> 4;
  int lrow = tid >> 2, lk = (tid & 3) * 8;
  float acc[4][4] = {};
  int am = m0 + lrow;
  long arow = (AMODE == 1) ? ((long)(am & 31) * 256 + at0 + (am >> 5)) : (long)am;
  const float* aptr = A + arow * (long)lda;
  bool mok = am < M;
  int bn = n0 + lrow;
  int gsrc = (BH > 0) ? ((bn & 3) * BH + (bn >> 2)) : bn;
  const float* bptr = Bw + (long)gsrc * (long)K;
  bool nok = bn < N;

  for (int k0 = 0; k0 < K; k0 += 32) {
    int kb = k0 + lk;
    if (kb + 8 <= K) {
      if (mok) {
        float4 v0 = *(const float4*)(aptr + kb);
        float4 v1 = *(const float4*)(aptr + kb + 4);
        As[lk + 0][lrow] = v0.x; As[lk + 1][lrow] = v0.y; As[lk + 2][lrow] = v0.z; As[lk + 3][lrow] = v0.w;
        As[lk + 4][lrow] = v1.x; As[lk + 5][lrow] = v1.y; As[lk + 6][lrow] = v1.z; As[lk + 7][lrow] = v1.w;
      } else {
#pragma unroll
        for (int i = 0; i < 8; i++) As[lk + i][lrow] = 0.f;
      }
      if (nok) {
        float4 v0 = *(const float4*)(bptr + kb);
        float4 v1 = *(const float4*)(bptr + kb + 4);
        Bs[lk + 0][lrow] = v0.x; Bs[lk + 1][lrow] = v0.y; Bs[lk + 2][lrow] = v0.z; Bs[lk + 3][lrow] = v0.w;
        Bs[lk + 4][lrow] = v1.x; Bs[lk + 5][lrow] = v1.y; Bs[lk + 6][lrow] = v1.z; Bs[lk + 7][lrow] = v1.w;
      } else {
#pragma unroll
        for (int i = 0; i < 8; i++) Bs[lk + i][lrow] = 0.f;
      }
    } else {
#pragma unroll
      for (int i = 0; i < 8; i++) {
        int k = kb + i;
        As[lk + i][lrow] = (mok && k < K) ? aptr[k] : 0.f;
        Bs[lk + i][lrow] = (nok && k < K) ? bptr[k] : 0.f;
      }
    }
    __syncthreads();
#pragma unroll
    for (int kk = 0; kk < 32; kk++) {
      float4 a = *(const float4*)&As[kk][tm * 4];
      float4 b = *(const float4*)&Bs[kk][tn * 4];
      FMA16(a, b, acc)
    }
    __syncthreads();
  }
#pragma unroll
  for (int i = 0; i < 4; i++) {
    int m = m0 + tm * 4 + i;
    if (m >= M) continue;
#pragma unroll
    for (int j = 0; j < 4; j++) {
      int n = n0 + tn * 4 + j;
      if (n >= N) continue;
      float v = acc[i][j];
      if (HASBIAS) {
        int gs = (BH > 0) ? ((n & 3) * BH + (n >> 2)) : n;
        v += bias[gs];
      }
      C[(long)m * ldc + n] = v;
    }
  }
}

// ---------------- split-bf16 MFMA GEMM: C = A * B^T (+bias) -----------------
// 64x64 tile, 256 threads (4 waves, each 32x32 = 2x2 16x16x32 frags, x3 split).
// Requires M%64==0, N%64==0 (K tail handled). A fp32 row-major (AMODE1 = dec
// chunk remap). B fp32 [N][K]; BH>0 applies unit-major row remap.
template <int AMODE, int BH, int HASBIAS>
__global__ __launch_bounds__(256) void mgemm_k(const float* __restrict__ A, int lda, int at0,
                                               const float* __restrict__ B,
                                               const float* __restrict__ bias,
                                               float* __restrict__ C, int ldc, int K) {
  __shared__ __align__(16) unsigned short Ah[64 * 40], Al[64 * 40], Bh[64 * 40], Bl[64 * 40];
  int tid = threadIdx.x;
  int m0 = blockIdx.x * 64, n0 = blockIdx.y * 64;
  int srow = tid >> 2, skoff = (tid & 3) * 8;
  int am = m0 + srow;
  long arow = (AMODE == 1) ? ((long)(am & 31) * 256 + at0 + (am >> 5)) : (long)am;
  const float* aptr = A + arow * (long)lda;
  int bn = n0 + srow;
  long gsrc;
  if (BH > 0) {
    int blk = bn / (4 * BH);
    int nl = bn - blk * 4 * BH;
    gsrc = (long)blk * 4 * BH + (nl & 3) * BH + (nl >> 2);
  } else gsrc = bn;
  const float* bptr = B + gsrc * (long)K;

  int lane = tid & 63, wv = tid >> 6;
  int wm = (wv >> 1) * 32, wn = (wv & 1) * 32;
  int fr = lane & 15, fk = (lane >> 4) * 8;
  int rbase = (lane >> 4) * 4;

  f32x4 acc[2][2] = {};
  for (int k0 = 0; k0 < K; k0 += 32) {
    int kb = k0 + skoff;
    float av[8], bv[8];
    if (kb + 8 <= K) {
      *(float4*)&av[0] = *(const float4*)(aptr + kb);
      *(float4*)&av[4] = *(const float4*)(aptr + kb + 4);
      *(float4*)&bv[0] = *(const float4*)(bptr + kb);
      *(float4*)&bv[4] = *(const float4*)(bptr + kb + 4);
    } else {
#pragma unroll
      for (int e = 0; e < 8; e++) {
        int k = kb + e;
        av[e] = (k < K) ? aptr[k] : 0.f;
        bv[e] = (k < K) ? bptr[k] : 0.f;
      }
    }
    unsigned short ha[8] __attribute__((aligned(16))), la[8] __attribute__((aligned(16)));
    unsigned short hb[8] __attribute__((aligned(16))), lb[8] __attribute__((aligned(16)));
#pragma unroll
    for (int e = 0; e < 8; e++) splitf(av[e], ha[e], la[e]);
#pragma unroll
    for (int e = 0; e < 8; e++) splitf(bv[e], hb[e], lb[e]);
    __syncthreads();
    *(uint4*)&Ah[srow * 40 + skoff] = *(const uint4*)ha;
    *(uint4*)&Al[srow * 40 + skoff] = *(const uint4*)la;
    *(uint4*)&Bh[srow * 40 + skoff] = *(const uint4*)hb;
    *(uint4*)&Bl[srow * 40 + skoff] = *(const uint4*)lb;
    __syncthreads();
    bf16x8 fah[2], fal[2], fbh[2], fbl[2];
#pragma unroll
    for (int i = 0; i < 2; i++) {
      fah[i] = *(const bf16x8*)&Ah[(wm + i * 16 + fr) * 40 + fk];
      fal[i] = *(const bf16x8*)&Al[(wm + i * 16 + fr) * 40 + fk];
      fbh[i] = *(const bf16x8*)&Bh[(wn + i * 16 + fr) * 40 + fk];
      fbl[i] = *(const bf16x8*)&Bl[(wn + i * 16 + fr) * 40 + fk];
    }
#pragma unroll
    for (int i = 0; i < 2; i++)
#pragma unroll
      for (int j = 0; j < 2; j++) {
        acc[i][j] = __builtin_amdgcn_mfma_f32_16x16x32_bf16(fah[i], fbh[j], acc[i][j], 0, 0, 0);
        acc[i][j] = __builtin_amdgcn_mfma_f32_16x16x32_bf16(fah[i], fbl[j], acc[i][j], 0, 0, 0);
        acc[i][j] = __builtin_amdgcn_mfma_f32_16x16x32_bf16(fal[i], fbh[j], acc[i][j], 0, 0, 0);
      }
  }
#pragma unroll
  for (int i = 0; i < 2; i++)
#pragma unroll
    for (int j = 0; j < 2; j++)
#pragma unroll
      for (int r = 0; r < 4; r++) {
        int m = m0 + wm + i * 16 + rbase + r;
        int n = n0 + wn + j * 16 + fr;
        float v = acc[i][j][r];
        if (HASBIAS) {
          long gs;
          if (BH > 0) {
            int blk = n / (4 * BH);
            int nl = n - blk * 4 * BH;
            gs = (long)blk * 4 * BH + (nl & 3) * BH + (nl >> 2);
          } else gs = n;
          v += bias[gs];
        }
        C[(long)m * ldc + n] = v;
      }
}

// ---------------- char-encoder fused step (split-bf16 MFMA + LSTM cell) -----
// grid (8, 64): m0 = seq tile (512 seqs), n0 = gate col tile (4096 = 2 dir x
// 2048 unit-major). A: k<K1 -> x (time-selected per dir), else h_in.
// Epilogue: dump gates to LDS (union with tiles), fused LSTM cell.
template <int K1>
__global__ __launch_bounds__(256) void mstep_k(
    const float* __restrict__ xF, const float* __restrict__ xB, int xstride,
    const float* __restrict__ Wx, const float* __restrict__ Wh,
    const float* __restrict__ bias,
    const float* __restrict__ h_in, float* __restrict__ h_out, float* __restrict__ c_st,
    float* __restrict__ out_base, int out_stride, int tF, int tB) {
  __shared__ __align__(16) char smem[20480];
  unsigned short* Ah = (unsigned short*)smem;
  unsigned short* Al = Ah + 2560;
  unsigned short* Bh = Ah + 5120;
  unsigned short* Bl = Ah + 7680;
  float* gbuf = (float*)smem;  // [64][68], used after MFMA loop

  int tid = threadIdx.x;
  int m0 = blockIdx.x * 64, n0 = blockIdx.y * 64;
  int dir = n0 >> 11;
  int srow = tid >> 2, skoff = (tid & 3) * 8;

  int am = m0 + srow;
  const float* xsel = dir ? xB : xF;
  const float* arow_x = xsel + (long)am * xstride;
  const float* arow_h = h_in + (long)dir * 262144 + (long)am * 512;

  int bn = n0 + srow;
  int nl = bn & 2047;
  long gsrc = (long)dir * 2048 + (nl & 3) * 512 + (nl >> 2);
  const float* brow_x = Wx + gsrc * (long)K1;
  const float* brow_h = Wh + gsrc * 512L;

  int lane = tid & 63, wv = tid >> 6;
  int wm = (wv >> 1) * 32, wn = (wv & 1) * 32;
  int fr = lane & 15, fk = (lane >> 4) * 8;
  int rbase = (lane >> 4) * 4;

  f32x4 acc[2][2] = {};
  const int K = K1 + 512;
  for (int k0 = 0; k0 < K; k0 += 32) {
    int kb = k0 + skoff;
    const float* ap = (kb < K1) ? (arow_x + kb) : (arow_h + (kb - K1));
    const float* bp = (kb < K1) ? (brow_x + kb) : (brow_h + (kb - K1));
    float av[8], bv[8];
    *(float4*)&av[0] = *(const float4*)ap;
    *(float4*)&av[4] = *(const float4*)(ap + 4);
    *(float4*)&bv[0] = *(const float4*)bp;
    *(float4*)&bv[4] = *(const float4*)(bp + 4);
    unsigned short ha[8] __attribute__((aligned(16))), la[8] __attribute__((aligned(16)));
    unsigned short hb[8] __attribute__((aligned(16))), lb[8] __attribute__((aligned(16)));
#pragma unroll
    for (int e = 0; e < 8; e++) splitf(av[e], ha[e], la[e]);
#pragma unroll
    for (int e = 0; e < 8; e++) splitf(bv[e], hb[e], lb[e]);
    __syncthreads();
    *(uint4*)&Ah[srow * 40 + skoff] = *(const uint4*)ha;
    *(uint4*)&Al[srow * 40 + skoff] = *(const uint4*)la;
    *(uint4*)&Bh[srow * 40 + skoff] = *(const uint4*)hb;
    *(uint4*)&Bl[srow * 40 + skoff] = *(const uint4*)lb;
    __syncthreads();
    bf16x8 fah[2], fal[2], fbh[2], fbl[2];
#pragma unroll
    for (int i = 0; i < 2; i++) {
      fah[i] = *(const bf16x8*)&Ah[(wm + i * 16 + fr) * 40 + fk];
      fal[i] = *(const bf16x8*)&Al[(wm + i * 16 + fr) * 40 + fk];
      fbh[i] = *(const bf16x8*)&Bh[(wn + i * 16 + fr) * 40 + fk];
      fbl[i] = *(const bf16x8*)&Bl[(wn + i * 16 + fr) * 40 + fk];
    }
#pragma unroll
    for (int i = 0; i < 2; i++)
#pragma unroll
      for (int j = 0; j < 2; j++) {
        acc[i][j] = __builtin_amdgcn_mfma_f32_16x16x32_bf16(fah[i], fbh[j], acc[i][j], 0, 0, 0);
        acc[i][j] = __builtin_amdgcn_mfma_f32_16x16x32_bf16(fah[i], fbl[j], acc[i][j], 0, 0, 0);
        acc[i][j] = __builtin_amdgcn_mfma_f32_16x16x32_bf16(fal[i], fbh[j], acc[i][j], 0, 0, 0);
      }
  }
  __syncthreads();  // tiles dead; reuse LDS as gate buffer
#pragma unroll
  for (int i = 0; i < 2; i++)
#pragma unroll
    for (int j = 0; j < 2; j++)
#pragma unroll
      for (int r = 0; r < 4; r++)
        gbuf[(wm + i * 16 + rbase + r) * 68 + (wn + j * 16 + fr)] = acc[i][j][r];
  __syncthreads();

  int ug0 = (n0 & 2047) >> 2;
  int t = dir ? tB : tF;
  for (int it = tid; it < 1024; it += 256) {
    int r = it >> 4, ul = it & 15;
    int seq = m0 + r, ug = ug0 + ul;
    float gi = gbuf[r * 68 + ul * 4 + 0] + bias[dir * 2048 + ug];
    float gf = gbuf[r * 68 + ul * 4 + 1] + bias[dir * 2048 + 512 + ug];
    float gg = gbuf[r * 68 + ul * 4 + 2] + bias[dir * 2048 + 1024 + ug];
    float go = gbuf[r * 68 + ul * 4 + 3] + bias[dir * 2048 + 1536 + ug];
    long ci = (long)dir * 262144 + (long)seq * 512 + ug;
    float c = sigf(gf) * c_st[ci] + sigf(gi) * tanhf(gg);
    float h = sigf(go) * tanhf(c);
    c_st[ci] = c;
    h_out[ci] = h;
    out_base[((long)seq * 16 + t) * out_stride + dir * 512 + ug] = h;
  }
}

// ---------------- sentence recurrent (persistent per (batch,dir) block) -----
__global__ __launch_bounds__(256) void sent_rec_k(const float* __restrict__ pre,
                                                  const float* __restrict__ WhT,
                                                  float* __restrict__ out) {
  int blk = blockIdx.x;
  int n = blk & 31, dir = blk >> 5;
  int tid = threadIdx.x;
  __shared__ float hls[256];
  __shared__ float gls[1024];
  float c = 0.f;
  hls[tid] = 0.f;
  __syncthreads();
  const float* whbase = WhT + (long)dir * 256 * 1024;
  int g4 = tid * 4;
  for (int s = 0; s < 16; s++) {
    int t = dir ? (15 - s) : s;
    const float* prow = pre + (long)(n * 16 + t) * 2048 + dir * 1024;
    float ax = 0.f, ay = 0.f, az = 0.f, aw = 0.f;
#pragma unroll 4
    for (int k = 0; k < 256; k++) {
      float hk = hls[k];
      float4 w = *(const float4*)(whbase + (long)k * 1024 + g4);
      ax += hk * w.x; ay += hk * w.y; az += hk * w.z; aw += hk * w.w;
    }
    float4 p = *(const float4*)(prow + g4);
    gls[g4 + 0] = ax + p.x; gls[g4 + 1] = ay + p.y;
    gls[g4 + 2] = az + p.z; gls[g4 + 3] = aw + p.w;
    __syncthreads();
    float gi = gls[tid], gf = gls[256 + tid], gg = gls[512 + tid], go = gls[768 + tid];
    c = sigf(gf) * c + sigf(gi) * tanhf(gg);
    float h = sigf(go) * tanhf(c);
    __syncthreads();
    hls[tid] = h;
    out[(long)n * 8192 + (long)t * 512 + dir * 256 + tid] = h;
    __syncthreads();
  }
}

// ---------------- decoder step ----------------------------------------------
__global__ __launch_bounds__(256) void dec_step_k(const float* __restrict__ WhTr,
                                                  const float* __restrict__ pre,
                                                  const float* __restrict__ h_in,
                                                  float* __restrict__ h_out,
                                                  float* __restrict__ c_st,
                                                  float* __restrict__ dec_out,
                                                  int tloc, int tglob) {
  int blk = blockIdx.x;
  int bs = blk & 1, ub = blk >> 1;
  int u0 = ub * 8;
  int n0 = u0 * 4;
  int tid = threadIdx.x;
  int p = tid & 15, bb = tid >> 4;
  int b = bs * 16 + bb;
  __shared__ float hls[16][1024];
  __shared__ float gls[16][32];
  for (int idx = tid; idx < 4096; idx += 256) {
    int bi = idx >> 8, k4 = idx & 255;
    *(float4*)&hls[bi][k4 * 4] = *(const float4*)(h_in + (long)(bs * 16 + bi) * 1024 + k4 * 4);
  }
  __syncthreads();
  int c0 = n0 + 2 * p;
  float a0 = 0.f, a1 = 0.f;
#pragma unroll 8
  for (int k = 0; k < 1024; k++) {
    float2 w = *(const float2*)(WhTr + (long)k * 4096 + c0);
    float h = hls[bb][k];
    a0 += h * w.x;
    a1 += h * w.y;
  }
  const float* pr = pre + ((long)tloc * 32 + b) * 4096;
  a0 += pr[c0];
  a1 += pr[c0 + 1];
  gls[bb][2 * p] = a0;
  gls[bb][2 * p + 1] = a1;
  __syncthreads();
  if (tid < 128) {
    int ul = tid & 7, bi = tid >> 3;
    int bg = bs * 16 + bi;
    float gi = gls[bi][ul * 4 + 0];
    float gf = gls[bi][ul * 4 + 1];
    float gg = gls[bi][ul * 4 + 2];
    float go = gls[bi][ul * 4 + 3];
    int u = u0 + ul;
    long ci = (long)bg * 1024 + u;
    float c = sigf(gf) * c_st[ci] + sigf(gi) * tanhf(gg);
    float h = sigf(go) * tanhf(c);
    c_st[ci] = c;
    h_out[ci] = h;
    dec_out[((long)bg * 256 + tglob) * 1024 + u] = h;
  }
}

// ---------------- attention (block per (b,i)) -------------------------------
__global__ __launch_bounds__(256) void attn_k(const float* __restrict__ sent_enc,
                                              const float* __restrict__ qbuf,
                                              const int* __restrict__ words,
                                              float* __restrict__ attn_out,
                                              float* __restrict__ finalb) {
  int b = blockIdx.x >> 4;
  int i = blockIdx.x & 15;
  int tid = threadIdx.x;
  __shared__ float se[16][512];
  __shared__ float qq[16][512];
  __shared__ float sc[16][16];
  __shared__ int kv[16];
  if (tid < 16) kv[tid] = 0;
  __syncthreads();
  {
    int j = tid >> 4, c = tid & 15;
    if (words[(b * 16 + j) * 16 + c] != 0) atomicOr(&kv[j], 1);
  }
  for (int idx = tid; idx < 16 * 128; idx += 256) {
    int j = idx >> 7, d4 = idx & 127;
    *(float4*)&se[j][d4 * 4] = *(const float4*)(sent_enc + (long)(b * 16 + j) * 512 + d4 * 4);
  }
  for (int idx = tid; idx < 16 * 128; idx += 256) {
    int c = idx >> 7, d4 = idx & 127;
    *(float4*)&qq[c][d4 * 4] = *(const float4*)(qbuf + (long)(b * 256 + i * 16 + c) * 512 + d4 * 4);
  }
  __syncthreads();
  int c = tid >> 4, j = tid & 15;
  {
    float s = 0.f;
#pragma unroll 4
    for (int k = 0; k < 512; k++) s += qq[c][k] * se[j][k];
    bool valid = (kv[j] != 0) && (j != i);
    sc[c][j] = valid ? s : -1e9f;
  }
  __syncthreads();
  float m = -INFINITY;
#pragma unroll
  for (int t = 0; t < 16; t++) m = fmaxf(m, sc[c][t]);
  float den = 0.f;
#pragma unroll
  for (int t = 0; t < 16; t++) den += expf(sc[c][t] - m);
  float a = expf(sc[c][j] - m) / den;
  __syncthreads();
  sc[c][j] = a;
  attn_out[((long)((b * 16 + i) * 16 + c)) * 16 + j] = a;
  __syncthreads();
  {
    int part = tid & 15;
    int cc = tid >> 4;
    for (int d = part * 32; d < part * 32 + 32; d++) {
      float v = 0.f;
#pragma unroll
      for (int jj = 0; jj < 16; jj++) v += sc[cc][jj] * se[jj][d];
      finalb[(long)(b * 256 + i * 16 + cc) * 1544 + d] = v;
    }
  }
}

// ---------------------------------------------------------------------------
extern "C" void kernel_launch(void* const* d_in, const int* in_sizes, int n_in,
                              void* d_out, int out_size, void* d_ws, size_t ws_size,
                              hipStream_t stream) {
  const int* sents = (const int*)d_in[0];
  const int* words = (const int*)d_in[1];
  const int* labels = (const int*)d_in[2];
  const float* word_embs = (const float*)d_in[3];
  const float* char_table = (const float*)d_in[4];
  const float* sent_Wx0 = (const float*)d_in[5];
  const float* sent_Wh0 = (const float*)d_in[6];
  const float* sent_b0 = (const float*)d_in[7];
  const float* sent_Wx1 = (const float*)d_in[8];
  const float* sent_Wh1 = (const float*)d_in[9];
  const float* sent_b1 = (const float*)d_in[10];
  const float* word_Wx0 = (const float*)d_in[11];
  const float* word_Wh0 = (const float*)d_in[12];
  const float* word_b0 = (const float*)d_in[13];
  const float* word_Wx1 = (const float*)d_in[14];
  const float* word_Wh1 = (const float*)d_in[15];
  const float* word_b1 = (const float*)d_in[16];
  const float* attn_Wq = (const float*)d_in[17];
  const float* dec_Wx = (const float*)d_in[18];
  const float* dec_Wh = (const float*)d_in[19];
  const float* dec_b = (const float*)d_in[20];
  const float* cls_W = (const float*)d_in[21];
  const float* cls_b = (const float*)d_in[22];

  float* ws = (float*)d_ws;
  float* wembs   = ws;                   // 153600
  float* preS    = wembs + 153600;       // 1048576
  float* hs0     = preS + 1048576;       // 262144
  float* sentenc = hs0 + 262144;         // 262144
  float* charin  = sentenc + 262144;     // 4456448 (reused: q, dec pre-chunk)
  float* hc0     = charin + 4456448;     // 8388608 (reused: dec_out)
  float* finalb  = hc0 + 8388608;        // 12648448
  float* hchar   = finalb + 12648448;    // 1048576  [2 par][2 dir][512][512]
  float* cchar   = hchar + 1048576;      // 524288
  float* hdec    = cchar + 524288;       // 65536    [2 par][32][1024]
  float* cdec    = hdec + 65536;         // 32768
  float* WhT0    = cdec + 32768;         // 524288   [2][256][1024]
  float* WhT1    = WhT0 + 524288;        // 524288
  float* WqT     = WhT1 + 524288;        // 524288   [512][1024]
  float* WhTr    = WqT + 524288;         // 4194304  [1024][4096]
  float* clsWT   = WhTr + 4194304;       // 15360    [15][1024]

  float* dout = (float*)d_out;
  float* diac = dout;              // 8192 x 15
  float* attnmap = dout + 122880;  // 32 x 16 x 16 x 16

  // ---- weight preprocessing -------------------------------------------------
  transpose_k<<<dim3(32, 8), 256, 0, stream>>>(sent_Wh0, WhT0, 1024, 256, 0);
  transpose_k<<<dim3(32, 8), 256, 0, stream>>>(sent_Wh0 + 262144, WhT0 + 262144, 1024, 256, 0);
  transpose_k<<<dim3(32, 8), 256, 0, stream>>>(sent_Wh1, WhT1, 1024, 256, 0);
  transpose_k<<<dim3(32, 8), 256, 0, stream>>>(sent_Wh1 + 262144, WhT1 + 262144, 1024, 256, 0);
  transpose_k<<<dim3(32, 16), 256, 0, stream>>>(attn_Wq, WqT, 1024, 512, 0);
  transpose_k<<<dim3(128, 32), 256, 0, stream>>>(dec_Wh, WhTr, 4096, 1024, 1024);
  transpose_k<<<dim3(32, 1), 256, 0, stream>>>(cls_W, clsWT, 1024, 15, 0);

  // ---- sentence encoder -----------------------------------------------------
  embed_k<<<600, 256, 0, stream>>>(sents, word_embs, wembs);
  gemm_k<0, 0, 1><<<dim3(8, 32), 256, 0, stream>>>(wembs, 300, 0, sent_Wx0, sent_b0,
                                                   preS, 2048, 512, 2048, 300);
  sent_rec_k<<<64, 256, 0, stream>>>(preS, WhT0, hs0);
  gemm_k<0, 0, 1><<<dim3(8, 32), 256, 0, stream>>>(hs0, 512, 0, sent_Wx1, sent_b1,
                                                   preS, 2048, 512, 2048, 512);
  sent_rec_k<<<64, 256, 0, stream>>>(preS, WhT1, sentenc);

  // ---- char encoder (split-bf16 MFMA fused steps) ---------------------------
  charin_k<<<17408, 256, 0, stream>>>(words, char_table, sentenc, charin);

  hipMemsetAsync(hchar, 0, (size_t)(1048576 + 524288) * 4, stream);
  for (int s = 0; s < 16; s++) {
    int p = s & 1;
    mstep_k<544><<<dim3(8, 64), 256, 0, stream>>>(
        charin + s * 544, charin + (15 - s) * 544, 16 * 544,
        word_Wx0, word_Wh0, word_b0,
        hchar + p * 524288, hchar + (p ^ 1) * 524288, cchar,
        hc0, 1024, s, 15 - s);
  }
  hipMemsetAsync(hchar, 0, (size_t)(1048576 + 524288) * 4, stream);
  for (int s = 0; s < 16; s++) {
    int p = s & 1;
    mstep_k<1024><<<dim3(8, 64), 256, 0, stream>>>(
        hc0 + s * 1024, hc0 + (15 - s) * 1024, 16 * 1024,
        word_Wx1, word_Wh1, word_b1,
        hchar + p * 524288, hchar + (p ^ 1) * 524288, cchar,
        finalb + 512, 1544, s, 15 - s);
  }

  // ---- attention ------------------------------------------------------------
  // q = char_enc (finalb cols 512..1536) @ Wq^T  -> charin (reused as q)
  mgemm_k<0, 0, 0><<<dim3(128, 8), 256, 0, stream>>>(finalb + 512, 1544, 0, WqT, nullptr,
                                                     charin, 512, 1024);
  attn_k<<<512, 256, 0, stream>>>(sentenc, charin, words, attnmap, finalb);
  labels_k<<<256, 256, 0, stream>>>(labels, finalb);

  // ---- decoder --------------------------------------------------------------
  hipMemsetAsync(hdec, 0, (size_t)(65536 + 32768) * 4, stream);
  for (int ch = 0; ch < 8; ch++) {
    // pre chunk: [32 tl][32 b][4096] = final(row b*256+t) @ dec_Wx^T + dec_b (unit-major)
    mgemm_k<1, 1024, 1><<<dim3(16, 64), 256, 0, stream>>>(finalb, 1544, ch * 32, dec_Wx, dec_b,
                                                          charin, 4096, 1544);
    for (int sl = 0; sl < 32; sl++) {
      int t = ch * 32 + sl;
      dec_step_k<<<256, 256, 0, stream>>>(WhTr, charin,
                                          hdec + (t & 1) * 32768, hdec + ((t & 1) ^ 1) * 32768,
                                          cdec, hc0 /* dec_out */, sl, t);
    }
  }

  // ---- classifier -----------------------------------------------------------
  gemm_k<0, 0, 1><<<dim3(128, 1), 256, 0, stream>>>(hc0, 1024, 0, clsWT, cls_b,
                                                    diac, 15, 8192, 15, 1024);
}

// Round 3
// 7969.459 us; speedup vs baseline: 2.3554x; 1.9836x over previous
//
#include <hip/hip_runtime.h>
#include <math.h>

// ---------------------------------------------------------------------------
// DiacritizerD3: split-bf16 MFMA pipeline, persistent-decoder version.
// B=32, TS=16, TW=16, SENT_H=256 (DIN=512), WORD_H=512 (DQ=DEC_H=1024),
// CDIM=32, WDIM=300, DEC_IN=1544.
// ---------------------------------------------------------------------------

typedef __attribute__((ext_vector_type(8))) __bf16 bf16x8;
typedef __attribute__((ext_vector_type(4))) float f32x4;

__device__ __forceinline__ float sigf(float x) { return 1.0f / (1.0f + expf(-x)); }

__device__ __forceinline__ unsigned short bf16rn(float x) {
  unsigned u = __float_as_uint(x);
  return (unsigned short)((u + 0x7fffu + ((u >> 16) & 1u)) >> 16);
}
__device__ __forceinline__ void splitf(float x, unsigned short& h, unsigned short& l) {
  h = bf16rn(x);
  float fh = __uint_as_float((unsigned)h << 16);
  l = bf16rn(x - fh);
}

#define FMA16(a, b, acc)                                                           \
  acc[0][0] += a.x * b.x; acc[0][1] += a.x * b.y; acc[0][2] += a.x * b.z; acc[0][3] += a.x * b.w; \
  acc[1][0] += a.y * b.x; acc[1][1] += a.y * b.y; acc[1][2] += a.y * b.z; acc[1][3] += a.y * b.w; \
  acc[2][0] += a.z * b.x; acc[2][1] += a.z * b.y; acc[2][2] += a.z * b.z; acc[2][3] += a.z * b.w; \
  acc[3][0] += a.w * b.x; acc[3][1] += a.w * b.y; acc[3][2] += a.w * b.z; acc[3][3] += a.w * b.w;

// ---------------- transpose ----------------
__global__ __launch_bounds__(256) void transpose_k(const float* __restrict__ in,
                                                   float* __restrict__ out,
                                                   int R, int C, int H) {
  __shared__ float tile[32][33];
  int r0 = blockIdx.x * 32, c0 = blockIdx.y * 32;
  int tx = threadIdx.x & 31, ty = threadIdx.x >> 5;
  for (int yy = ty; yy < 32; yy += 8) {
    int r = r0 + yy, c = c0 + tx;
    float v = 0.f;
    if (r < R && c < C) {
      int gs = H ? ((r & 3) * H + (r >> 2)) : r;
      v = in[(long)gs * C + c];
    }
    tile[yy][tx] = v;
  }
  __syncthreads();
  for (int yy = ty; yy < 32; yy += 8) {
    int c = c0 + yy, r = r0 + tx;
    if (r < R && c < C) out[(long)c * R + r] = tile[tx][yy];
  }
}

// ---------------- embedding lookup ----------------
__global__ void embed_k(const int* __restrict__ sents, const float* __restrict__ word_embs,
                        float* __restrict__ wembs) {
  int idx = blockIdx.x * 256 + threadIdx.x;
  if (idx >= 512 * 300) return;
  int r = idx / 300, k = idx - r * 300;
  wembs[idx] = word_embs[(long)sents[r] * 300 + k];
}

// ---------------- char-encoder input build (writes bf16 hi/lo pairs) --------
__global__ void charin_k(const int* __restrict__ words, const float* __restrict__ char_table,
                         const float* __restrict__ sent_enc,
                         unsigned short* __restrict__ ciH, unsigned short* __restrict__ ciL) {
  int idx = blockIdx.x * 256 + threadIdx.x;
  if (idx >= 512 * 16 * 544) return;
  int k = idx % 544;
  int rc = idx / 544;
  int c = rc & 15, n = rc >> 4;
  int w = words[n * 16 + c];
  float v;
  if (k < 32) v = char_table[w * 32 + k];
  else v = (w != 0) ? sent_enc[n * 512 + (k - 32)] : 0.f;
  unsigned short h, l;
  splitf(v, h, l);
  ciH[idx] = h; ciL[idx] = l;
}

// ---------------- labels -> final[:,1536:1544] (pairs) ----------------------
__global__ void labels_k(const int* __restrict__ labels,
                         unsigned short* __restrict__ fH, unsigned short* __restrict__ fL) {
  int idx = blockIdx.x * 256 + threadIdx.x;
  if (idx >= 8192 * 8) return;
  int r = idx >> 3, l = idx & 7;
  long o = (long)r * 1544 + 1536 + l;
  fH[o] = bf16rn((float)labels[idx]);
  fL[o] = 0;
}

// ---------------- dec_Wh -> fragment-contiguous split layout ----------------
// WhF[nt][kt][lane][8]: col = nt*16+(lane&15) (unit-major), k = kt*32+((lane>>4)&3)*8+j
__global__ void decwh_prep_k(const float* __restrict__ dec_Wh,
                             unsigned short* __restrict__ WhFH,
                             unsigned short* __restrict__ WhFL) {
  long o = (long)blockIdx.x * 256 + threadIdx.x;
  if (o >= 4194304) return;
  int j = (int)(o & 7);
  int lane = (int)((o >> 3) & 63);
  int kt = (int)((o >> 9) & 31);
  int nt = (int)(o >> 14);
  int col = nt * 16 + (lane & 15);
  int gsrc = (col & 3) * 1024 + (col >> 2);
  int k = kt * 32 + ((lane >> 4) & 3) * 8 + j;
  float v = dec_Wh[(long)gsrc * 1024 + k];
  unsigned short h, l;
  splitf(v, h, l);
  WhFH[o] = h; WhFL[o] = l;
}

// ---------------- fp32 fallback GEMM (sentence Wx, classifier) --------------
template <int HASBIAS>
__global__ __launch_bounds__(256) void gemm_k(const float* __restrict__ A, int lda,
                                              const float* __restrict__ Bw,
                                              const float* __restrict__ bias,
                                              float* __restrict__ C, int ldc,
                                              int M, int N, int K) {
  __shared__ float As[32][64];
  __shared__ float Bs[32][64];
  int tid = threadIdx.x;
  int m0 = blockIdx.x * 64, n0 = blockIdx.y * 64;
  int tn = tid & 15, tm = tid >> 4;
  int lrow = tid >> 2, lk = (tid & 3) * 8;
  float acc[4][4] = {};
  int am = m0 + lrow;
  const float* aptr = A + (long)am * lda;
  bool mok = am < M;
  int bn = n0 + lrow;
  const float* bptr = Bw + (long)bn * K;
  bool nok = bn < N;

  for (int k0 = 0; k0 < K; k0 += 32) {
    int kb = k0 + lk;
    if (kb + 8 <= K) {
      if (mok) {
        float4 v0 = *(const float4*)(aptr + kb);
        float4 v1 = *(const float4*)(aptr + kb + 4);
        As[lk + 0][lrow] = v0.x; As[lk + 1][lrow] = v0.y; As[lk + 2][lrow] = v0.z; As[lk + 3][lrow] = v0.w;
        As[lk + 4][lrow] = v1.x; As[lk + 5][lrow] = v1.y; As[lk + 6][lrow] = v1.z; As[lk + 7][lrow] = v1.w;
      } else {
#pragma unroll
        for (int i = 0; i < 8; i++) As[lk + i][lrow] = 0.f;
      }
      if (nok) {
        float4 v0 = *(const float4*)(bptr + kb);
        float4 v1 = *(const float4*)(bptr + kb + 4);
        Bs[lk + 0][lrow] = v0.x; Bs[lk + 1][lrow] = v0.y; Bs[lk + 2][lrow] = v0.z; Bs[lk + 3][lrow] = v0.w;
        Bs[lk + 4][lrow] = v1.x; Bs[lk + 5][lrow] = v1.y; Bs[lk + 6][lrow] = v1.z; Bs[lk + 7][lrow] = v1.w;
      } else {
#pragma unroll
        for (int i = 0; i < 8; i++) Bs[lk + i][lrow] = 0.f;
      }
    } else {
#pragma unroll
      for (int i = 0; i < 8; i++) {
        int k = kb + i;
        As[lk + i][lrow] = (mok && k < K) ? aptr[k] : 0.f;
        Bs[lk + i][lrow] = (nok && k < K) ? bptr[k] : 0.f;
      }
    }
    __syncthreads();
#pragma unroll
    for (int kk = 0; kk < 32; kk++) {
      float4 a = *(const float4*)&As[kk][tm * 4];
      float4 b = *(const float4*)&Bs[kk][tn * 4];
      FMA16(a, b, acc)
    }
    __syncthreads();
  }
#pragma unroll
  for (int i = 0; i < 4; i++) {
    int m = m0 + tm * 4 + i;
    if (m >= M) continue;
#pragma unroll
    for (int j = 0; j < 4; j++) {
      int n = n0 + tn * 4 + j;
      if (n >= N) continue;
      float v = acc[i][j];
      if (HASBIAS) v += bias[n];
      C[(long)m * ldc + n] = v;
    }
  }
}

// ---------------- split-bf16 MFMA GEMM, pre-split A: C = A * B^T (+bias) ----
// A: bf16 hi/lo pairs, row-major (AMODE1 = decoder chunk remap of rows).
// B: fp32 [N][K], split in-kernel; BH>0 applies unit-major row remap.
template <int AMODE, int BH, int HASBIAS>
__global__ __launch_bounds__(256) void mgemm_k(const unsigned short* __restrict__ AH,
                                               const unsigned short* __restrict__ AL,
                                               int lda, int at0,
                                               const float* __restrict__ B,
                                               const float* __restrict__ bias,
                                               float* __restrict__ C, int ldc, int K) {
  __shared__ __align__(16) unsigned short Ah[64 * 40], Al[64 * 40], Bh[64 * 40], Bl[64 * 40];
  int tid = threadIdx.x;
  int m0 = blockIdx.x * 64, n0 = blockIdx.y * 64;
  int srow = tid >> 2, skoff = (tid & 3) * 8;
  int am = m0 + srow;
  long arow = (AMODE == 1) ? ((long)(am & 31) * 256 + at0 + (am >> 5)) : (long)am;
  const unsigned short* aptrH = AH + arow * (long)lda;
  const unsigned short* aptrL = AL + arow * (long)lda;
  int bn = n0 + srow;
  long gsrc;
  if (BH > 0) gsrc = (long)(bn & 3) * BH + (bn >> 2);
  else gsrc = bn;
  const float* bptr = B + gsrc * (long)K;

  int lane = tid & 63, wv = tid >> 6;
  int wm = (wv >> 1) * 32, wn = (wv & 1) * 32;
  int fr = lane & 15, fk = (lane >> 4) * 8;
  int rbase = (lane >> 4) * 4;

  f32x4 acc[2][2] = {};
  for (int k0 = 0; k0 < K; k0 += 32) {
    int kb = k0 + skoff;
    uint4 vh, vl;
    unsigned short hb[8] __attribute__((aligned(16))), lb[8] __attribute__((aligned(16)));
    if (kb + 8 <= K) {
      vh = *(const uint4*)(aptrH + kb);
      vl = *(const uint4*)(aptrL + kb);
      float4 b0 = *(const float4*)(bptr + kb);
      float4 b1 = *(const float4*)(bptr + kb + 4);
      float bv[8] = {b0.x, b0.y, b0.z, b0.w, b1.x, b1.y, b1.z, b1.w};
#pragma unroll
      for (int e = 0; e < 8; e++) splitf(bv[e], hb[e], lb[e]);
    } else {
      unsigned short ea[8] __attribute__((aligned(16))), el[8] __attribute__((aligned(16)));
#pragma unroll
      for (int e = 0; e < 8; e++) {
        int k = kb + e;
        ea[e] = (k < K) ? aptrH[k] : 0;
        el[e] = (k < K) ? aptrL[k] : 0;
        float bvv = (k < K) ? bptr[k] : 0.f;
        splitf(bvv, hb[e], lb[e]);
      }
      vh = *(const uint4*)ea;
      vl = *(const uint4*)el;
    }
    __syncthreads();
    *(uint4*)&Ah[srow * 40 + skoff] = vh;
    *(uint4*)&Al[srow * 40 + skoff] = vl;
    *(uint4*)&Bh[srow * 40 + skoff] = *(const uint4*)hb;
    *(uint4*)&Bl[srow * 40 + skoff] = *(const uint4*)lb;
    __syncthreads();
    bf16x8 fah[2], fal[2], fbh[2], fbl[2];
#pragma unroll
    for (int i = 0; i < 2; i++) {
      fah[i] = *(const bf16x8*)&Ah[(wm + i * 16 + fr) * 40 + fk];
      fal[i] = *(const bf16x8*)&Al[(wm + i * 16 + fr) * 40 + fk];
      fbh[i] = *(const bf16x8*)&Bh[(wn + i * 16 + fr) * 40 + fk];
      fbl[i] = *(const bf16x8*)&Bl[(wn + i * 16 + fr) * 40 + fk];
    }
#pragma unroll
    for (int i = 0; i < 2; i++)
#pragma unroll
      for (int j = 0; j < 2; j++) {
        acc[i][j] = __builtin_amdgcn_mfma_f32_16x16x32_bf16(fah[i], fbh[j], acc[i][j], 0, 0, 0);
        acc[i][j] = __builtin_amdgcn_mfma_f32_16x16x32_bf16(fah[i], fbl[j], acc[i][j], 0, 0, 0);
        acc[i][j] = __builtin_amdgcn_mfma_f32_16x16x32_bf16(fal[i], fbh[j], acc[i][j], 0, 0, 0);
      }
  }
#pragma unroll
  for (int i = 0; i < 2; i++)
#pragma unroll
    for (int j = 0; j < 2; j++)
#pragma unroll
      for (int r = 0; r < 4; r++) {
        int m = m0 + wm + i * 16 + rbase + r;
        int n = n0 + wn + j * 16 + fr;
        float v = acc[i][j][r];
        if (HASBIAS) {
          long gs = (BH > 0) ? ((long)(n & 3) * BH + (n >> 2)) : (long)n;
          v += bias[gs];
        }
        C[(long)m * ldc + n] = v;
      }
}

// ---------------- char-encoder fused step (pre-split A, MFMA, LSTM cell) ----
template <int K1>
__global__ __launch_bounds__(256) void mstep_k(
    const unsigned short* __restrict__ xFH, const unsigned short* __restrict__ xFL,
    const unsigned short* __restrict__ xBH, const unsigned short* __restrict__ xBL,
    int xstride,
    const float* __restrict__ Wx, const float* __restrict__ Wh,
    const float* __restrict__ bias,
    const unsigned short* __restrict__ hInH, const unsigned short* __restrict__ hInL,
    unsigned short* __restrict__ hOutH, unsigned short* __restrict__ hOutL,
    float* __restrict__ c_st,
    unsigned short* __restrict__ outH, unsigned short* __restrict__ outL,
    int out_stride, int tF, int tB) {
  __shared__ __align__(16) char smem[20480];
  unsigned short* Ah = (unsigned short*)smem;
  unsigned short* Al = Ah + 2560;
  unsigned short* Bh = Ah + 5120;
  unsigned short* Bl = Ah + 7680;
  float* gbuf = (float*)smem;  // [64][68] after MFMA loop (17408 B)

  int tid = threadIdx.x;
  int m0 = blockIdx.x * 64, n0 = blockIdx.y * 64;
  int dir = n0 >> 11;
  int nn0 = n0 & 2047;
  int srow = tid >> 2, skoff = (tid & 3) * 8;

  int am = m0 + srow;
  const unsigned short* axH = dir ? xBH : xFH;
  const unsigned short* axL = dir ? xBL : xFL;
  const unsigned short* arow_xH = axH + (long)am * xstride;
  const unsigned short* arow_xL = axL + (long)am * xstride;
  const unsigned short* arow_hH = hInH + (long)dir * 262144 + (long)am * 512;
  const unsigned short* arow_hL = hInL + (long)dir * 262144 + (long)am * 512;

  int bn = nn0 + srow;
  long gsrc = (long)dir * 2048 + (bn & 3) * 512 + (bn >> 2);
  const float* brow_x = Wx + gsrc * (long)K1;
  const float* brow_h = Wh + gsrc * 512L;

  int lane = tid & 63, wv = tid >> 6;
  int wm = (wv >> 1) * 32, wn = (wv & 1) * 32;
  int fr = lane & 15, fk = (lane >> 4) * 8;
  int rbase = (lane >> 4) * 4;

  f32x4 acc[2][2] = {};
  const int K = K1 + 512;
  for (int k0 = 0; k0 < K; k0 += 32) {
    int kb = k0 + skoff;
    uint4 vh, vl;
    const float* bp;
    if (kb < K1) {
      vh = *(const uint4*)(arow_xH + kb);
      vl = *(const uint4*)(arow_xL + kb);
      bp = brow_x + kb;
    } else {
      vh = *(const uint4*)(arow_hH + (kb - K1));
      vl = *(const uint4*)(arow_hL + (kb - K1));
      bp = brow_h + (kb - K1);
    }
    float4 b0 = *(const float4*)bp;
    float4 b1 = *(const float4*)(bp + 4);
    float bv[8] = {b0.x, b0.y, b0.z, b0.w, b1.x, b1.y, b1.z, b1.w};
    unsigned short hb[8] __attribute__((aligned(16))), lb[8] __attribute__((aligned(16)));
#pragma unroll
    for (int e = 0; e < 8; e++) splitf(bv[e], hb[e], lb[e]);
    __syncthreads();
    *(uint4*)&Ah[srow * 40 + skoff] = vh;
    *(uint4*)&Al[srow * 40 + skoff] = vl;
    *(uint4*)&Bh[srow * 40 + skoff] = *(const uint4*)hb;
    *(uint4*)&Bl[srow * 40 + skoff] = *(const uint4*)lb;
    __syncthreads();
    bf16x8 fah[2], fal[2], fbh[2], fbl[2];
#pragma unroll
    for (int i = 0; i < 2; i++) {
      fah[i] = *(const bf16x8*)&Ah[(wm + i * 16 + fr) * 40 + fk];
      fal[i] = *(const bf16x8*)&Al[(wm + i * 16 + fr) * 40 + fk];
      fbh[i] = *(const bf16x8*)&Bh[(wn + i * 16 + fr) * 40 + fk];
      fbl[i] = *(const bf16x8*)&Bl[(wn + i * 16 + fr) * 40 + fk];
    }
#pragma unroll
    for (int i = 0; i < 2; i++)
#pragma unroll
      for (int j = 0; j < 2; j++) {
        acc[i][j] = __builtin_amdgcn_mfma_f32_16x16x32_bf16(fah[i], fbh[j], acc[i][j], 0, 0, 0);
        acc[i][j] = __builtin_amdgcn_mfma_f32_16x16x32_bf16(fah[i], fbl[j], acc[i][j], 0, 0, 0);
        acc[i][j] = __builtin_amdgcn_mfma_f32_16x16x32_bf16(fal[i], fbh[j], acc[i][j], 0, 0, 0);
      }
  }
  __syncthreads();  // tiles dead; reuse LDS as gate buffer
#pragma unroll
  for (int i = 0; i < 2; i++)
#pragma unroll
    for (int j = 0; j < 2; j++)
#pragma unroll
      for (int r = 0; r < 4; r++)
        gbuf[(wm + i * 16 + rbase + r) * 68 + (wn + j * 16 + fr)] = acc[i][j][r];
  __syncthreads();

  int ug0 = nn0 >> 2;
  int t = dir ? tB : tF;
  for (int it = tid; it < 1024; it += 256) {
    int r = it >> 4, ul = it & 15;
    int seq = m0 + r, ug = ug0 + ul;
    float gi = gbuf[r * 68 + ul * 4 + 0] + bias[dir * 2048 + ug];
    float gf = gbuf[r * 68 + ul * 4 + 1] + bias[dir * 2048 + 512 + ug];
    float gg = gbuf[r * 68 + ul * 4 + 2] + bias[dir * 2048 + 1024 + ug];
    float go = gbuf[r * 68 + ul * 4 + 3] + bias[dir * 2048 + 1536 + ug];
    long ci = (long)dir * 262144 + (long)seq * 512 + ug;
    float c = sigf(gf) * c_st[ci] + sigf(gi) * tanhf(gg);
    float h = sigf(go) * tanhf(c);
    c_st[ci] = c;
    unsigned short hh, hl;
    splitf(h, hh, hl);
    hOutH[ci] = hh;
    hOutL[ci] = hl;
    long oo = ((long)seq * 16 + t) * out_stride + dir * 512 + ug;
    outH[oo] = hh;
    outL[oo] = hl;
  }
}

// ---------------- sentence recurrent ----------------
__global__ __launch_bounds__(256) void sent_rec_k(const float* __restrict__ pre,
                                                  const float* __restrict__ WhT,
                                                  float* __restrict__ out) {
  int blk = blockIdx.x;
  int n = blk & 31, dir = blk >> 5;
  int tid = threadIdx.x;
  __shared__ float hls[256];
  __shared__ float gls[1024];
  float c = 0.f;
  hls[tid] = 0.f;
  __syncthreads();
  const float* whbase = WhT + (long)dir * 256 * 1024;
  int g4 = tid * 4;
  for (int s = 0; s < 16; s++) {
    int t = dir ? (15 - s) : s;
    const float* prow = pre + (long)(n * 16 + t) * 2048 + dir * 1024;
    float ax = 0.f, ay = 0.f, az = 0.f, aw = 0.f;
#pragma unroll 4
    for (int k = 0; k < 256; k++) {
      float hk = hls[k];
      float4 w = *(const float4*)(whbase + (long)k * 1024 + g4);
      ax += hk * w.x; ay += hk * w.y; az += hk * w.z; aw += hk * w.w;
    }
    float4 p = *(const float4*)(prow + g4);
    gls[g4 + 0] = ax + p.x; gls[g4 + 1] = ay + p.y;
    gls[g4 + 2] = az + p.z; gls[g4 + 3] = aw + p.w;
    __syncthreads();
    float gi = gls[tid], gf = gls[256 + tid], gg = gls[512 + tid], go = gls[768 + tid];
    c = sigf(gf) * c + sigf(gi) * tanhf(gg);
    float h = sigf(go) * tanhf(c);
    __syncthreads();
    hls[tid] = h;
    out[(long)n * 8192 + (long)t * 512 + dir * 256 + tid] = h;
    __syncthreads();
  }
}

// ---------------- persistent decoder: 32 steps, grid barrier ----------------
// 128 blocks x 256 thr. Block bid: gate-cols [bid*32, bid*32+32) (units bid*8..+8),
// all 32 batches. Waves: (mh = wv>>1) batch half, (nh = wv&1) col half.
// WhF: fragment-contiguous split weights. h state: bf16 hi/lo ping-pong.
__global__ __launch_bounds__(256) void dec_persist_k(
    const unsigned short* __restrict__ WhFH, const unsigned short* __restrict__ WhFL,
    const float* __restrict__ pre,
    unsigned short* __restrict__ hH, unsigned short* __restrict__ hL,
    float* __restrict__ c_st, float* __restrict__ dec_out,
    int* __restrict__ cnt, int tbase) {
  __shared__ float gbuf[32][33];
  int tid = threadIdx.x, bid = blockIdx.x;
  int lane = tid & 63, wv = tid >> 6;
  int mh = wv >> 1, nh = wv & 1;
  int fr = lane & 15, fkq = (lane >> 4) & 3;
  int fk = fkq * 8;
  int arow = mh * 16 + fr;
  // cell mapping: one thread per (batch, unit-local)
  int ul = tid & 7, bb = tid >> 3;
  int u = bid * 8 + ul;
  float c = c_st[bb * 1024 + u];
  const unsigned short* wbH = WhFH + ((long)(bid * 2 + nh) * 32) * 512;
  const unsigned short* wbL = WhFL + ((long)(bid * 2 + nh) * 32) * 512;

  for (int tl = 0; tl < 32; tl++) {
    int t = tbase + tl;
    const unsigned short* hInH = hH + (long)(t & 1) * 32768;
    const unsigned short* hInL = hL + (long)(t & 1) * 32768;
    unsigned short* hOutH = hH + (long)((t + 1) & 1) * 32768;
    unsigned short* hOutL = hL + (long)((t + 1) & 1) * 32768;
    f32x4 acc0 = {0.f, 0.f, 0.f, 0.f};
    f32x4 acc1 = {0.f, 0.f, 0.f, 0.f};
#pragma unroll 8
    for (int kt = 0; kt < 32; kt += 2) {
      long ao = (long)arow * 1024 + kt * 32 + fk;
      bf16x8 ah0 = *(const bf16x8*)&hInH[ao];
      bf16x8 al0 = *(const bf16x8*)&hInL[ao];
      bf16x8 bh0 = *(const bf16x8*)&wbH[kt * 512 + lane * 8];
      bf16x8 bl0 = *(const bf16x8*)&wbL[kt * 512 + lane * 8];
      bf16x8 ah1 = *(const bf16x8*)&hInH[ao + 32];
      bf16x8 al1 = *(const bf16x8*)&hInL[ao + 32];
      bf16x8 bh1 = *(const bf16x8*)&wbH[(kt + 1) * 512 + lane * 8];
      bf16x8 bl1 = *(const bf16x8*)&wbL[(kt + 1) * 512 + lane * 8];
      acc0 = __builtin_amdgcn_mfma_f32_16x16x32_bf16(ah0, bh0, acc0, 0, 0, 0);
      acc1 = __builtin_amdgcn_mfma_f32_16x16x32_bf16(ah1, bh1, acc1, 0, 0, 0);
      acc0 = __builtin_amdgcn_mfma_f32_16x16x32_bf16(ah0, bl0, acc0, 0, 0, 0);
      acc1 = __builtin_amdgcn_mfma_f32_16x16x32_bf16(ah1, bl1, acc1, 0, 0, 0);
      acc0 = __builtin_amdgcn_mfma_f32_16x16x32_bf16(al0, bh0, acc0, 0, 0, 0);
      acc1 = __builtin_amdgcn_mfma_f32_16x16x32_bf16(al1, bh1, acc1, 0, 0, 0);
    }
#pragma unroll
    for (int r = 0; r < 4; r++)
      gbuf[mh * 16 + fkq * 4 + r][nh * 16 + fr] = acc0[r] + acc1[r];
    __syncthreads();
    {
      const float* pr = pre + ((long)tl * 32 + bb) * 4096 + bid * 32 + ul * 4;
      float4 p = *(const float4*)pr;
      float gi = gbuf[bb][ul * 4 + 0] + p.x;
      float gf = gbuf[bb][ul * 4 + 1] + p.y;
      float gg = gbuf[bb][ul * 4 + 2] + p.z;
      float go = gbuf[bb][ul * 4 + 3] + p.w;
      c = sigf(gf) * c + sigf(gi) * tanhf(gg);
      float h = sigf(go) * tanhf(c);
      unsigned short hh, hl;
      splitf(h, hh, hl);
      hOutH[bb * 1024 + u] = hh;
      hOutL[bb * 1024 + u] = hl;
      dec_out[((long)bb * 256 + t) * 1024 + u] = h;
    }
    __syncthreads();  // gbuf safe for next iter
    if (tl < 31) {
      if (tid == 0) {
        __threadfence();
        __hip_atomic_fetch_add(cnt, 1, __ATOMIC_RELAXED, __HIP_MEMORY_SCOPE_AGENT);
        int target = 128 * (tl + 1);
        while (__hip_atomic_load(cnt, __ATOMIC_RELAXED, __HIP_MEMORY_SCOPE_AGENT) < target) {}
        __threadfence();
      }
      __syncthreads();
    }
  }
  c_st[bb * 1024 + u] = c;
}

// ---------------- attention ----------------
__global__ __launch_bounds__(256) void attn_k(const float* __restrict__ sent_enc,
                                              const float* __restrict__ qbuf,
                                              const int* __restrict__ words,
                                              float* __restrict__ attn_out,
                                              unsigned short* __restrict__ fH,
                                              unsigned short* __restrict__ fL) {
  int b = blockIdx.x >> 4;
  int i = blockIdx.x & 15;
  int tid = threadIdx.x;
  __shared__ float se[16][512];
  __shared__ float qq[16][512];
  __shared__ float sc[16][16];
  __shared__ int kv[16];
  if (tid < 16) kv[tid] = 0;
  __syncthreads();
  {
    int j = tid >> 4, c = tid & 15;
    if (words[(b * 16 + j) * 16 + c] != 0) atomicOr(&kv[j], 1);
  }
  for (int idx = tid; idx < 16 * 128; idx += 256) {
    int j = idx >> 7, d4 = idx & 127;
    *(float4*)&se[j][d4 * 4] = *(const float4*)(sent_enc + (long)(b * 16 + j) * 512 + d4 * 4);
  }
  for (int idx = tid; idx < 16 * 128; idx += 256) {
    int c = idx >> 7, d4 = idx & 127;
    *(float4*)&qq[c][d4 * 4] = *(const float4*)(qbuf + (long)(b * 256 + i * 16 + c) * 512 + d4 * 4);
  }
  __syncthreads();
  int c = tid >> 4, j = tid & 15;
  {
    float s = 0.f;
#pragma unroll 4
    for (int k = 0; k < 512; k++) s += qq[c][k] * se[j][k];
    bool valid = (kv[j] != 0) && (j != i);
    sc[c][j] = valid ? s : -1e9f;
  }
  __syncthreads();
  float m = -INFINITY;
#pragma unroll
  for (int t = 0; t < 16; t++) m = fmaxf(m, sc[c][t]);
  float den = 0.f;
#pragma unroll
  for (int t = 0; t < 16; t++) den += expf(sc[c][t] - m);
  float a = expf(sc[c][j] - m) / den;
  __syncthreads();
  sc[c][j] = a;
  attn_out[((long)((b * 16 + i) * 16 + c)) * 16 + j] = a;
  __syncthreads();
  {
    int part = tid & 15;
    int cc = tid >> 4;
    for (int d = part * 32; d < part * 32 + 32; d++) {
      float v = 0.f;
#pragma unroll
      for (int jj = 0; jj < 16; jj++) v += sc[cc][jj] * se[jj][d];
      long o = (long)(b * 256 + i * 16 + cc) * 1544 + d;
      unsigned short hh, hl;
      splitf(v, hh, hl);
      fH[o] = hh;
      fL[o] = hl;
    }
  }
}

// ---------------------------------------------------------------------------
extern "C" void kernel_launch(void* const* d_in, const int* in_sizes, int n_in,
                              void* d_out, int out_size, void* d_ws, size_t ws_size,
                              hipStream_t stream) {
  const int* sents = (const int*)d_in[0];
  const int* words = (const int*)d_in[1];
  const int* labels = (const int*)d_in[2];
  const float* word_embs = (const float*)d_in[3];
  const float* char_table = (const float*)d_in[4];
  const float* sent_Wx0 = (const float*)d_in[5];
  const float* sent_Wh0 = (const float*)d_in[6];
  const float* sent_b0 = (const float*)d_in[7];
  const float* sent_Wx1 = (const float*)d_in[8];
  const float* sent_Wh1 = (const float*)d_in[9];
  const float* sent_b1 = (const float*)d_in[10];
  const float* word_Wx0 = (const float*)d_in[11];
  const float* word_Wh0 = (const float*)d_in[12];
  const float* word_b0 = (const float*)d_in[13];
  const float* word_Wx1 = (const float*)d_in[14];
  const float* word_Wh1 = (const float*)d_in[15];
  const float* word_b1 = (const float*)d_in[16];
  const float* attn_Wq = (const float*)d_in[17];
  const float* dec_Wx = (const float*)d_in[18];
  const float* dec_Wh = (const float*)d_in[19];
  const float* dec_b = (const float*)d_in[20];
  const float* cls_W = (const float*)d_in[21];
  const float* cls_b = (const float*)d_in[22];

  char* base = (char*)d_ws;
  // ---- Slot Z (early phase; overlaid by WhF pairs during decoder) ---------
  float* wembs   = (float*)(base + 0);          // 153600 fl
  float* preS    = (float*)(base + 614400);     // 1048576 fl
  float* hs0     = (float*)(base + 4808704);    // 262144 fl
  float* WhT0    = (float*)(base + 5857280);    // 524288 fl
  float* WhT1    = (float*)(base + 7954432);    // 524288 fl
  float* sentenc = (float*)(base + 10051584);   // 262144 fl
  unsigned short* hcharH = (unsigned short*)(base + 11100160);  // 1048576 us
  unsigned short* hcharL = (unsigned short*)(base + 13197312);  // 1048576 us
  float* cchar   = (float*)(base + 15294464);   // 524288 fl  (Z ends 17391616)
  unsigned short* WhFH = (unsigned short*)(base + 0);        // 4194304 us (overlay)
  unsigned short* WhFL = (unsigned short*)(base + 8388608);  // 4194304 us
  // ---- Slot W: finalb pairs ----------------------------------------------
  unsigned short* finalbH = (unsigned short*)(base + 17391616);  // 12648448 us
  unsigned short* finalbL = (unsigned short*)(base + 42688512);  // 12648448 us
  // ---- Slot Y: q (attn) then pre-chunk (decoder), 4194304 fl --------------
  float* qbuf = (float*)(base + 67985408);
  float* pre  = qbuf;
  // ---- WqT ----------------------------------------------------------------
  float* WqT = (float*)(base + 84762624);       // 524288 fl
  // ---- Slot X (char phase; overlaid by decoder/classifier buffers) --------
  unsigned short* charinH = (unsigned short*)(base + 86859776);   // 4456448 us
  unsigned short* charinL = (unsigned short*)(base + 95772672);   // 4456448 us
  unsigned short* hc0H = (unsigned short*)(base + 104685568);     // 8388608 us
  unsigned short* hc0L = (unsigned short*)(base + 121462784);     // 8388608 us (X ends 138240000)
  float* dec_out = (float*)(base + 86859776);                     // 8388608 fl (overlay)
  unsigned short* hdecH = (unsigned short*)(base + 120414208);    // 65536 us
  unsigned short* hdecL = (unsigned short*)(base + 120545280);    // 65536 us
  float* c_dec = (float*)(base + 120676352);                      // 32768 fl
  float* clsWT = (float*)(base + 120807424);                      // 15360 fl
  int* cnt = (int*)(base + 120868864);

  float* dout = (float*)d_out;
  float* diac = dout;              // 8192 x 15
  float* attnmap = dout + 122880;  // 32 x 16 x 16 x 16

  // ---- weight preprocessing (sentence + attention) --------------------------
  transpose_k<<<dim3(32, 8), 256, 0, stream>>>(sent_Wh0, WhT0, 1024, 256, 0);
  transpose_k<<<dim3(32, 8), 256, 0, stream>>>(sent_Wh0 + 262144, WhT0 + 262144, 1024, 256, 0);
  transpose_k<<<dim3(32, 8), 256, 0, stream>>>(sent_Wh1, WhT1, 1024, 256, 0);
  transpose_k<<<dim3(32, 8), 256, 0, stream>>>(sent_Wh1 + 262144, WhT1 + 262144, 1024, 256, 0);
  transpose_k<<<dim3(32, 16), 256, 0, stream>>>(attn_Wq, WqT, 1024, 512, 0);

  // ---- sentence encoder -----------------------------------------------------
  embed_k<<<600, 256, 0, stream>>>(sents, word_embs, wembs);
  gemm_k<1><<<dim3(8, 32), 256, 0, stream>>>(wembs, 300, sent_Wx0, sent_b0,
                                             preS, 2048, 512, 2048, 300);
  sent_rec_k<<<64, 256, 0, stream>>>(preS, WhT0, hs0);
  gemm_k<1><<<dim3(8, 32), 256, 0, stream>>>(hs0, 512, sent_Wx1, sent_b1,
                                             preS, 2048, 512, 2048, 512);
  sent_rec_k<<<64, 256, 0, stream>>>(preS, WhT1, sentenc);

  // ---- char encoder ---------------------------------------------------------
  charin_k<<<17408, 256, 0, stream>>>(words, char_table, sentenc, charinH, charinL);

  hipMemsetAsync(base + 11100160, 0, 6291456, stream);  // hcharH/L + cchar
  for (int s = 0; s < 16; s++) {
    int p = s & 1;
    mstep_k<544><<<dim3(8, 64), 256, 0, stream>>>(
        charinH + s * 544, charinL + s * 544,
        charinH + (15 - s) * 544, charinL + (15 - s) * 544, 16 * 544,
        word_Wx0, word_Wh0, word_b0,
        hcharH + p * 524288, hcharL + p * 524288,
        hcharH + (p ^ 1) * 524288, hcharL + (p ^ 1) * 524288, cchar,
        hc0H, hc0L, 1024, s, 15 - s);
  }
  hipMemsetAsync(base + 11100160, 0, 6291456, stream);
  for (int s = 0; s < 16; s++) {
    int p = s & 1;
    mstep_k<1024><<<dim3(8, 64), 256, 0, stream>>>(
        hc0H + s * 1024, hc0L + s * 1024,
        hc0H + (15 - s) * 1024, hc0L + (15 - s) * 1024, 16 * 1024,
        word_Wx1, word_Wh1, word_b1,
        hcharH + p * 524288, hcharL + p * 524288,
        hcharH + (p ^ 1) * 524288, hcharL + (p ^ 1) * 524288, cchar,
        finalbH + 512, finalbL + 512, 1544, s, 15 - s);
  }

  // ---- attention ------------------------------------------------------------
  mgemm_k<0, 0, 0><<<dim3(128, 8), 256, 0, stream>>>(finalbH + 512, finalbL + 512, 1544, 0,
                                                     WqT, nullptr, qbuf, 512, 1024);
  attn_k<<<512, 256, 0, stream>>>(sentenc, qbuf, words, attnmap, finalbH, finalbL);
  labels_k<<<256, 256, 0, stream>>>(labels, finalbH, finalbL);

  // ---- decoder --------------------------------------------------------------
  decwh_prep_k<<<16384, 256, 0, stream>>>(dec_Wh, WhFH, WhFL);  // overlays Slot Z
  hipMemsetAsync(base + 120414208, 0, 393216, stream);          // hdecH/L + c_dec
  for (int ch = 0; ch < 8; ch++) {
    mgemm_k<1, 1024, 1><<<dim3(16, 64), 256, 0, stream>>>(finalbH, finalbL, 1544, ch * 32,
                                                          dec_Wx, dec_b, pre, 4096, 1544);
    hipMemsetAsync(cnt, 0, 256, stream);
    dec_persist_k<<<128, 256, 0, stream>>>(WhFH, WhFL, pre, hdecH, hdecL,
                                           c_dec, dec_out, cnt, ch * 32);
  }

  // ---- classifier -----------------------------------------------------------
  transpose_k<<<dim3(32, 1), 256, 0, stream>>>(cls_W, clsWT, 1024, 15, 0);
  gemm_k<1><<<dim3(128, 1), 256, 0, stream>>>(dec_out, 1024, clsWT, cls_b,
                                              diac, 15, 8192, 15, 1024);
}

// Round 4
// 7582.728 us; speedup vs baseline: 2.4756x; 1.0510x over previous
//
#include <hip/hip_runtime.h>
#include <math.h>

// ---------------------------------------------------------------------------
// DiacritizerD3: split-bf16 MFMA pipeline, persistent decoder w/ register-
// resident weights. B=32, TS=16, TW=16, SENT_H=256 (DIN=512), WORD_H=512
// (DQ=DEC_H=1024), CDIM=32, WDIM=300, DEC_IN=1544.
// ---------------------------------------------------------------------------

typedef __attribute__((ext_vector_type(8))) __bf16 bf16x8;
typedef __attribute__((ext_vector_type(4))) float f32x4;

__device__ __forceinline__ float sigf(float x) { return 1.0f / (1.0f + expf(-x)); }

__device__ __forceinline__ unsigned short bf16rn(float x) {
  unsigned u = __float_as_uint(x);
  return (unsigned short)((u + 0x7fffu + ((u >> 16) & 1u)) >> 16);
}
__device__ __forceinline__ void splitf(float x, unsigned short& h, unsigned short& l) {
  h = bf16rn(x);
  float fh = __uint_as_float((unsigned)h << 16);
  l = bf16rn(x - fh);
}

#define FMA16(a, b, acc)                                                           \
  acc[0][0] += a.x * b.x; acc[0][1] += a.x * b.y; acc[0][2] += a.x * b.z; acc[0][3] += a.x * b.w; \
  acc[1][0] += a.y * b.x; acc[1][1] += a.y * b.y; acc[1][2] += a.y * b.z; acc[1][3] += a.y * b.w; \
  acc[2][0] += a.z * b.x; acc[2][1] += a.z * b.y; acc[2][2] += a.z * b.z; acc[2][3] += a.z * b.w; \
  acc[3][0] += a.w * b.x; acc[3][1] += a.w * b.y; acc[3][2] += a.w * b.z; acc[3][3] += a.w * b.w;

// ---------------- transpose ----------------
__global__ __launch_bounds__(256) void transpose_k(const float* __restrict__ in,
                                                   float* __restrict__ out,
                                                   int R, int C, int H) {
  __shared__ float tile[32][33];
  int r0 = blockIdx.x * 32, c0 = blockIdx.y * 32;
  int tx = threadIdx.x & 31, ty = threadIdx.x >> 5;
  for (int yy = ty; yy < 32; yy += 8) {
    int r = r0 + yy, c = c0 + tx;
    float v = 0.f;
    if (r < R && c < C) {
      int gs = H ? ((r & 3) * H + (r >> 2)) : r;
      v = in[(long)gs * C + c];
    }
    tile[yy][tx] = v;
  }
  __syncthreads();
  for (int yy = ty; yy < 32; yy += 8) {
    int c = c0 + yy, r = r0 + tx;
    if (r < R && c < C) out[(long)c * R + r] = tile[tx][yy];
  }
}

// ---------------- embedding lookup ----------------
__global__ void embed_k(const int* __restrict__ sents, const float* __restrict__ word_embs,
                        float* __restrict__ wembs) {
  int idx = blockIdx.x * 256 + threadIdx.x;
  if (idx >= 512 * 300) return;
  int r = idx / 300, k = idx - r * 300;
  wembs[idx] = word_embs[(long)sents[r] * 300 + k];
}

// ---------------- char-encoder input build (writes bf16 hi/lo pairs) --------
__global__ void charin_k(const int* __restrict__ words, const float* __restrict__ char_table,
                         const float* __restrict__ sent_enc,
                         unsigned short* __restrict__ ciH, unsigned short* __restrict__ ciL) {
  int idx = blockIdx.x * 256 + threadIdx.x;
  if (idx >= 512 * 16 * 544) return;
  int k = idx % 544;
  int rc = idx / 544;
  int c = rc & 15, n = rc >> 4;
  int w = words[n * 16 + c];
  float v;
  if (k < 32) v = char_table[w * 32 + k];
  else v = (w != 0) ? sent_enc[n * 512 + (k - 32)] : 0.f;
  unsigned short h, l;
  splitf(v, h, l);
  ciH[idx] = h; ciL[idx] = l;
}

// ---------------- labels -> final[:,1536:1544] (pairs) ----------------------
__global__ void labels_k(const int* __restrict__ labels,
                         unsigned short* __restrict__ fH, unsigned short* __restrict__ fL) {
  int idx = blockIdx.x * 256 + threadIdx.x;
  if (idx >= 8192 * 8) return;
  int r = idx >> 3, l = idx & 7;
  long o = (long)r * 1544 + 1536 + l;
  fH[o] = bf16rn((float)labels[idx]);
  fL[o] = 0;
}

// ---------------- dec_Wh -> fragment-contiguous split layout ----------------
// WhF[nt][kt][lane][8]: col = nt*16+(lane&15) (unit-major), k = kt*32+((lane>>4)&3)*8+j
__global__ void decwh_prep_k(const float* __restrict__ dec_Wh,
                             unsigned short* __restrict__ WhFH,
                             unsigned short* __restrict__ WhFL) {
  long o = (long)blockIdx.x * 256 + threadIdx.x;
  if (o >= 4194304) return;
  int j = (int)(o & 7);
  int lane = (int)((o >> 3) & 63);
  int kt = (int)((o >> 9) & 31);
  int nt = (int)(o >> 14);
  int col = nt * 16 + (lane & 15);
  int gsrc = (col & 3) * 1024 + (col >> 2);
  int k = kt * 32 + ((lane >> 4) & 3) * 8 + j;
  float v = dec_Wh[(long)gsrc * 1024 + k];
  unsigned short h, l;
  splitf(v, h, l);
  WhFH[o] = h; WhFL[o] = l;
}

// ---------------- fp32 fallback GEMM (sentence Wx, classifier) --------------
template <int HASBIAS>
__global__ __launch_bounds__(256) void gemm_k(const float* __restrict__ A, int lda,
                                              const float* __restrict__ Bw,
                                              const float* __restrict__ bias,
                                              float* __restrict__ C, int ldc,
                                              int M, int N, int K) {
  __shared__ float As[32][64];
  __shared__ float Bs[32][64];
  int tid = threadIdx.x;
  int m0 = blockIdx.x * 64, n0 = blockIdx.y * 64;
  int tn = tid & 15, tm = tid >> 4;
  int lrow = tid >> 2, lk = (tid & 3) * 8;
  float acc[4][4] = {};
  int am = m0 + lrow;
  const float* aptr = A + (long)am * lda;
  bool mok = am < M;
  int bn = n0 + lrow;
  const float* bptr = Bw + (long)bn * K;
  bool nok = bn < N;

  for (int k0 = 0; k0 < K; k0 += 32) {
    int kb = k0 + lk;
    if (kb + 8 <= K) {
      if (mok) {
        float4 v0 = *(const float4*)(aptr + kb);
        float4 v1 = *(const float4*)(aptr + kb + 4);
        As[lk + 0][lrow] = v0.x; As[lk + 1][lrow] = v0.y; As[lk + 2][lrow] = v0.z; As[lk + 3][lrow] = v0.w;
        As[lk + 4][lrow] = v1.x; As[lk + 5][lrow] = v1.y; As[lk + 6][lrow] = v1.z; As[lk + 7][lrow] = v1.w;
      } else {
#pragma unroll
        for (int i = 0; i < 8; i++) As[lk + i][lrow] = 0.f;
      }
      if (nok) {
        float4 v0 = *(const float4*)(bptr + kb);
        float4 v1 = *(const float4*)(bptr + kb + 4);
        Bs[lk + 0][lrow] = v0.x; Bs[lk + 1][lrow] = v0.y; Bs[lk + 2][lrow] = v0.z; Bs[lk + 3][lrow] = v0.w;
        Bs[lk + 4][lrow] = v1.x; Bs[lk + 5][lrow] = v1.y; Bs[lk + 6][lrow] = v1.z; Bs[lk + 7][lrow] = v1.w;
      } else {
#pragma unroll
        for (int i = 0; i < 8; i++) Bs[lk + i][lrow] = 0.f;
      }
    } else {
#pragma unroll
      for (int i = 0; i < 8; i++) {
        int k = kb + i;
        As[lk + i][lrow] = (mok && k < K) ? aptr[k] : 0.f;
        Bs[lk + i][lrow] = (nok && k < K) ? bptr[k] : 0.f;
      }
    }
    __syncthreads();
#pragma unroll
    for (int kk = 0; kk < 32; kk++) {
      float4 a = *(const float4*)&As[kk][tm * 4];
      float4 b = *(const float4*)&Bs[kk][tn * 4];
      FMA16(a, b, acc)
    }
    __syncthreads();
  }
#pragma unroll
  for (int i = 0; i < 4; i++) {
    int m = m0 + tm * 4 + i;
    if (m >= M) continue;
#pragma unroll
    for (int j = 0; j < 4; j++) {
      int n = n0 + tn * 4 + j;
      if (n >= N) continue;
      float v = acc[i][j];
      if (HASBIAS) v += bias[n];
      C[(long)m * ldc + n] = v;
    }
  }
}

// ---------------- split-bf16 MFMA GEMM, pre-split A: C = A * B^T (+bias) ----
template <int AMODE, int BH, int HASBIAS>
__global__ __launch_bounds__(256) void mgemm_k(const unsigned short* __restrict__ AH,
                                               const unsigned short* __restrict__ AL,
                                               int lda, int at0,
                                               const float* __restrict__ B,
                                               const float* __restrict__ bias,
                                               float* __restrict__ C, int ldc, int K) {
  __shared__ __align__(16) unsigned short Ah[64 * 40], Al[64 * 40], Bh[64 * 40], Bl[64 * 40];
  int tid = threadIdx.x;
  int m0 = blockIdx.x * 64, n0 = blockIdx.y * 64;
  int srow = tid >> 2, skoff = (tid & 3) * 8;
  int am = m0 + srow;
  long arow = (AMODE == 1) ? ((long)(am & 31) * 256 + at0 + (am >> 5)) : (long)am;
  const unsigned short* aptrH = AH + arow * (long)lda;
  const unsigned short* aptrL = AL + arow * (long)lda;
  int bn = n0 + srow;
  long gsrc;
  if (BH > 0) gsrc = (long)(bn & 3) * BH + (bn >> 2);
  else gsrc = bn;
  const float* bptr = B + gsrc * (long)K;

  int lane = tid & 63, wv = tid >> 6;
  int wm = (wv >> 1) * 32, wn = (wv & 1) * 32;
  int fr = lane & 15, fk = (lane >> 4) * 8;
  int rbase = (lane >> 4) * 4;

  f32x4 acc[2][2] = {};
  for (int k0 = 0; k0 < K; k0 += 32) {
    int kb = k0 + skoff;
    uint4 vh, vl;
    unsigned short hb[8] __attribute__((aligned(16))), lb[8] __attribute__((aligned(16)));
    if (kb + 8 <= K) {
      vh = *(const uint4*)(aptrH + kb);
      vl = *(const uint4*)(aptrL + kb);
      float4 b0 = *(const float4*)(bptr + kb);
      float4 b1 = *(const float4*)(bptr + kb + 4);
      float bv[8] = {b0.x, b0.y, b0.z, b0.w, b1.x, b1.y, b1.z, b1.w};
#pragma unroll
      for (int e = 0; e < 8; e++) splitf(bv[e], hb[e], lb[e]);
    } else {
      unsigned short ea[8] __attribute__((aligned(16))), el[8] __attribute__((aligned(16)));
#pragma unroll
      for (int e = 0; e < 8; e++) {
        int k = kb + e;
        ea[e] = (k < K) ? aptrH[k] : 0;
        el[e] = (k < K) ? aptrL[k] : 0;
        float bvv = (k < K) ? bptr[k] : 0.f;
        splitf(bvv, hb[e], lb[e]);
      }
      vh = *(const uint4*)ea;
      vl = *(const uint4*)el;
    }
    __syncthreads();
    *(uint4*)&Ah[srow * 40 + skoff] = vh;
    *(uint4*)&Al[srow * 40 + skoff] = vl;
    *(uint4*)&Bh[srow * 40 + skoff] = *(const uint4*)hb;
    *(uint4*)&Bl[srow * 40 + skoff] = *(const uint4*)lb;
    __syncthreads();
    bf16x8 fah[2], fal[2], fbh[2], fbl[2];
#pragma unroll
    for (int i = 0; i < 2; i++) {
      fah[i] = *(const bf16x8*)&Ah[(wm + i * 16 + fr) * 40 + fk];
      fal[i] = *(const bf16x8*)&Al[(wm + i * 16 + fr) * 40 + fk];
      fbh[i] = *(const bf16x8*)&Bh[(wn + i * 16 + fr) * 40 + fk];
      fbl[i] = *(const bf16x8*)&Bl[(wn + i * 16 + fr) * 40 + fk];
    }
#pragma unroll
    for (int i = 0; i < 2; i++)
#pragma unroll
      for (int j = 0; j < 2; j++) {
        acc[i][j] = __builtin_amdgcn_mfma_f32_16x16x32_bf16(fah[i], fbh[j], acc[i][j], 0, 0, 0);
        acc[i][j] = __builtin_amdgcn_mfma_f32_16x16x32_bf16(fah[i], fbl[j], acc[i][j], 0, 0, 0);
        acc[i][j] = __builtin_amdgcn_mfma_f32_16x16x32_bf16(fal[i], fbh[j], acc[i][j], 0, 0, 0);
      }
  }
#pragma unroll
  for (int i = 0; i < 2; i++)
#pragma unroll
    for (int j = 0; j < 2; j++)
#pragma unroll
      for (int r = 0; r < 4; r++) {
        int m = m0 + wm + i * 16 + rbase + r;
        int n = n0 + wn + j * 16 + fr;
        float v = acc[i][j][r];
        if (HASBIAS) {
          long gs = (BH > 0) ? ((long)(n & 3) * BH + (n >> 2)) : (long)n;
          v += bias[gs];
        }
        C[(long)m * ldc + n] = v;
      }
}

// ---------------- char-encoder fused step (pre-split A, MFMA, LSTM cell) ----
template <int K1>
__global__ __launch_bounds__(256) void mstep_k(
    const unsigned short* __restrict__ xFH, const unsigned short* __restrict__ xFL,
    const unsigned short* __restrict__ xBH, const unsigned short* __restrict__ xBL,
    int xstride,
    const float* __restrict__ Wx, const float* __restrict__ Wh,
    const float* __restrict__ bias,
    const unsigned short* __restrict__ hInH, const unsigned short* __restrict__ hInL,
    unsigned short* __restrict__ hOutH, unsigned short* __restrict__ hOutL,
    float* __restrict__ c_st,
    unsigned short* __restrict__ outH, unsigned short* __restrict__ outL,
    int out_stride, int tF, int tB) {
  __shared__ __align__(16) char smem[20480];
  unsigned short* Ah = (unsigned short*)smem;
  unsigned short* Al = Ah + 2560;
  unsigned short* Bh = Ah + 5120;
  unsigned short* Bl = Ah + 7680;
  float* gbuf = (float*)smem;  // [64][68] after MFMA loop (17408 B)

  int tid = threadIdx.x;
  int m0 = blockIdx.x * 64, n0 = blockIdx.y * 64;
  int dir = n0 >> 11;
  int nn0 = n0 & 2047;
  int srow = tid >> 2, skoff = (tid & 3) * 8;

  int am = m0 + srow;
  const unsigned short* axH = dir ? xBH : xFH;
  const unsigned short* axL = dir ? xBL : xFL;
  const unsigned short* arow_xH = axH + (long)am * xstride;
  const unsigned short* arow_xL = axL + (long)am * xstride;
  const unsigned short* arow_hH = hInH + (long)dir * 262144 + (long)am * 512;
  const unsigned short* arow_hL = hInL + (long)dir * 262144 + (long)am * 512;

  int bn = nn0 + srow;
  long gsrc = (long)dir * 2048 + (bn & 3) * 512 + (bn >> 2);
  const float* brow_x = Wx + gsrc * (long)K1;
  const float* brow_h = Wh + gsrc * 512L;

  int lane = tid & 63, wv = tid >> 6;
  int wm = (wv >> 1) * 32, wn = (wv & 1) * 32;
  int fr = lane & 15, fk = (lane >> 4) * 8;
  int rbase = (lane >> 4) * 4;

  f32x4 acc[2][2] = {};
  const int K = K1 + 512;
  for (int k0 = 0; k0 < K; k0 += 32) {
    int kb = k0 + skoff;
    uint4 vh, vl;
    const float* bp;
    if (kb < K1) {
      vh = *(const uint4*)(arow_xH + kb);
      vl = *(const uint4*)(arow_xL + kb);
      bp = brow_x + kb;
    } else {
      vh = *(const uint4*)(arow_hH + (kb - K1));
      vl = *(const uint4*)(arow_hL + (kb - K1));
      bp = brow_h + (kb - K1);
    }
    float4 b0 = *(const float4*)bp;
    float4 b1 = *(const float4*)(bp + 4);
    float bv[8] = {b0.x, b0.y, b0.z, b0.w, b1.x, b1.y, b1.z, b1.w};
    unsigned short hb[8] __attribute__((aligned(16))), lb[8] __attribute__((aligned(16)));
#pragma unroll
    for (int e = 0; e < 8; e++) splitf(bv[e], hb[e], lb[e]);
    __syncthreads();
    *(uint4*)&Ah[srow * 40 + skoff] = vh;
    *(uint4*)&Al[srow * 40 + skoff] = vl;
    *(uint4*)&Bh[srow * 40 + skoff] = *(const uint4*)hb;
    *(uint4*)&Bl[srow * 40 + skoff] = *(const uint4*)lb;
    __syncthreads();
    bf16x8 fah[2], fal[2], fbh[2], fbl[2];
#pragma unroll
    for (int i = 0; i < 2; i++) {
      fah[i] = *(const bf16x8*)&Ah[(wm + i * 16 + fr) * 40 + fk];
      fal[i] = *(const bf16x8*)&Al[(wm + i * 16 + fr) * 40 + fk];
      fbh[i] = *(const bf16x8*)&Bh[(wn + i * 16 + fr) * 40 + fk];
      fbl[i] = *(const bf16x8*)&Bl[(wn + i * 16 + fr) * 40 + fk];
    }
#pragma unroll
    for (int i = 0; i < 2; i++)
#pragma unroll
      for (int j = 0; j < 2; j++) {
        acc[i][j] = __builtin_amdgcn_mfma_f32_16x16x32_bf16(fah[i], fbh[j], acc[i][j], 0, 0, 0);
        acc[i][j] = __builtin_amdgcn_mfma_f32_16x16x32_bf16(fah[i], fbl[j], acc[i][j], 0, 0, 0);
        acc[i][j] = __builtin_amdgcn_mfma_f32_16x16x32_bf16(fal[i], fbh[j], acc[i][j], 0, 0, 0);
      }
  }
  __syncthreads();  // tiles dead; reuse LDS as gate buffer
#pragma unroll
  for (int i = 0; i < 2; i++)
#pragma unroll
    for (int j = 0; j < 2; j++)
#pragma unroll
      for (int r = 0; r < 4; r++)
        gbuf[(wm + i * 16 + rbase + r) * 68 + (wn + j * 16 + fr)] = acc[i][j][r];
  __syncthreads();

  int ug0 = nn0 >> 2;
  int t = dir ? tB : tF;
  for (int it = tid; it < 1024; it += 256) {
    int r = it >> 4, ul = it & 15;
    int seq = m0 + r, ug = ug0 + ul;
    float gi = gbuf[r * 68 + ul * 4 + 0] + bias[dir * 2048 + ug];
    float gf = gbuf[r * 68 + ul * 4 + 1] + bias[dir * 2048 + 512 + ug];
    float gg = gbuf[r * 68 + ul * 4 + 2] + bias[dir * 2048 + 1024 + ug];
    float go = gbuf[r * 68 + ul * 4 + 3] + bias[dir * 2048 + 1536 + ug];
    long ci = (long)dir * 262144 + (long)seq * 512 + ug;
    float c = sigf(gf) * c_st[ci] + sigf(gi) * tanhf(gg);
    float h = sigf(go) * tanhf(c);
    c_st[ci] = c;
    unsigned short hh, hl;
    splitf(h, hh, hl);
    hOutH[ci] = hh;
    hOutL[ci] = hl;
    long oo = ((long)seq * 16 + t) * out_stride + dir * 512 + ug;
    outH[oo] = hh;
    outL[oo] = hl;
  }
}

// ---------------- sentence recurrent ----------------
__global__ __launch_bounds__(256) void sent_rec_k(const float* __restrict__ pre,
                                                  const float* __restrict__ WhT,
                                                  float* __restrict__ out) {
  int blk = blockIdx.x;
  int n = blk & 31, dir = blk >> 5;
  int tid = threadIdx.x;
  __shared__ float hls[256];
  __shared__ float gls[1024];
  float c = 0.f;
  hls[tid] = 0.f;
  __syncthreads();
  const float* whbase = WhT + (long)dir * 256 * 1024;
  int g4 = tid * 4;
  for (int s = 0; s < 16; s++) {
    int t = dir ? (15 - s) : s;
    const float* prow = pre + (long)(n * 16 + t) * 2048 + dir * 1024;
    float ax = 0.f, ay = 0.f, az = 0.f, aw = 0.f;
#pragma unroll 4
    for (int k = 0; k < 256; k++) {
      float hk = hls[k];
      float4 w = *(const float4*)(whbase + (long)k * 1024 + g4);
      ax += hk * w.x; ay += hk * w.y; az += hk * w.z; aw += hk * w.w;
    }
    float4 p = *(const float4*)(prow + g4);
    gls[g4 + 0] = ax + p.x; gls[g4 + 1] = ay + p.y;
    gls[g4 + 2] = az + p.z; gls[g4 + 3] = aw + p.w;
    __syncthreads();
    float gi = gls[tid], gf = gls[256 + tid], gg = gls[512 + tid], go = gls[768 + tid];
    c = sigf(gf) * c + sigf(gi) * tanhf(gg);
    float h = sigf(go) * tanhf(c);
    __syncthreads();
    hls[tid] = h;
    out[(long)n * 8192 + (long)t * 512 + dir * 256 + tid] = h;
    __syncthreads();
  }
}

// ---------------- persistent decoder: 32 steps, register-resident weights ---
// 128 blocks x 256 thr. Block bid: gate-cols [bid*32, bid*32+32) (units
// bid*8..+8), all 32 batches. Waves: nh = wv&1 (16-col half), kh = wv>>1
// (512-K half). Per wave: weights bf16x8 wH[16]/wL[16] in VGPRs (survive the
// grid-barrier fence that invalidates L1/L2 each step — this was the 16 MB/
// step refetch in R3). Cross-kh reduce via LDS; fused cell.
__global__ __launch_bounds__(256, 1) void dec_persist_k(
    const unsigned short* __restrict__ WhFH, const unsigned short* __restrict__ WhFL,
    const float* __restrict__ pre,
    unsigned short* __restrict__ hH, unsigned short* __restrict__ hL,
    float* __restrict__ c_st, float* __restrict__ dec_out,
    int* __restrict__ cnt, int tbase) {
  __shared__ float gbuf[2][32][33];
  int tid = threadIdx.x, bid = blockIdx.x;
  int lane = tid & 63, wv = tid >> 6;
  int nh = wv & 1, kh = wv >> 1;
  int fr = lane & 15, fq = (lane >> 4) & 3;

  // weight preload into registers: nt = bid*2+nh, kt = kh*16+i
  bf16x8 wH[16], wL[16];
  {
    long wbase = ((long)(bid * 2 + nh) * 32 + kh * 16) * 512 + lane * 8;
#pragma unroll
    for (int i = 0; i < 16; i++) {
      wH[i] = *(const bf16x8*)&WhFH[wbase + i * 512];
      wL[i] = *(const bf16x8*)&WhFL[wbase + i * 512];
    }
  }

  // cell mapping: one thread per (batch bb, unit-local ul)
  int ul = tid & 7, bb = tid >> 3;
  int u = bid * 8 + ul;
  float c = c_st[bb * 1024 + u];

  for (int tl = 0; tl < 32; tl++) {
    int t = tbase + tl;
    const unsigned short* hInH = hH + (long)(t & 1) * 32768;
    const unsigned short* hInL = hL + (long)(t & 1) * 32768;
    unsigned short* hOutH = hH + (long)((t + 1) & 1) * 32768;
    unsigned short* hOutL = hL + (long)((t + 1) & 1) * 32768;
    f32x4 acc0 = {0.f, 0.f, 0.f, 0.f};  // batches 0..15
    f32x4 acc1 = {0.f, 0.f, 0.f, 0.f};  // batches 16..31
#pragma unroll
    for (int i = 0; i < 16; i++) {
      int k = (kh * 16 + i) * 32 + fq * 8;
      long a0 = (long)fr * 1024 + k;
      long a1 = (long)(16 + fr) * 1024 + k;
      bf16x8 ah0 = *(const bf16x8*)&hInH[a0];
      bf16x8 al0 = *(const bf16x8*)&hInL[a0];
      bf16x8 ah1 = *(const bf16x8*)&hInH[a1];
      bf16x8 al1 = *(const bf16x8*)&hInL[a1];
      acc0 = __builtin_amdgcn_mfma_f32_16x16x32_bf16(ah0, wH[i], acc0, 0, 0, 0);
      acc1 = __builtin_amdgcn_mfma_f32_16x16x32_bf16(ah1, wH[i], acc1, 0, 0, 0);
      acc0 = __builtin_amdgcn_mfma_f32_16x16x32_bf16(ah0, wL[i], acc0, 0, 0, 0);
      acc1 = __builtin_amdgcn_mfma_f32_16x16x32_bf16(ah1, wL[i], acc1, 0, 0, 0);
      acc0 = __builtin_amdgcn_mfma_f32_16x16x32_bf16(al0, wH[i], acc0, 0, 0, 0);
      acc1 = __builtin_amdgcn_mfma_f32_16x16x32_bf16(al1, wH[i], acc1, 0, 0, 0);
    }
#pragma unroll
    for (int r = 0; r < 4; r++) {
      gbuf[kh][fq * 4 + r][nh * 16 + fr] = acc0[r];
      gbuf[kh][16 + fq * 4 + r][nh * 16 + fr] = acc1[r];
    }
    __syncthreads();
    {
      const float* pr = pre + ((long)tl * 32 + bb) * 4096 + bid * 32 + ul * 4;
      float4 p = *(const float4*)pr;
      float gi = gbuf[0][bb][ul * 4 + 0] + gbuf[1][bb][ul * 4 + 0] + p.x;
      float gf = gbuf[0][bb][ul * 4 + 1] + gbuf[1][bb][ul * 4 + 1] + p.y;
      float gg = gbuf[0][bb][ul * 4 + 2] + gbuf[1][bb][ul * 4 + 2] + p.z;
      float go = gbuf[0][bb][ul * 4 + 3] + gbuf[1][bb][ul * 4 + 3] + p.w;
      c = sigf(gf) * c + sigf(gi) * tanhf(gg);
      float h = sigf(go) * tanhf(c);
      unsigned short hh, hl;
      splitf(h, hh, hl);
      hOutH[bb * 1024 + u] = hh;
      hOutL[bb * 1024 + u] = hl;
      dec_out[((long)bb * 256 + t) * 1024 + u] = h;
    }
    __syncthreads();  // gbuf safe for next iter
    if (tl < 31) {
      if (tid == 0) {
        __threadfence();
        __hip_atomic_fetch_add(cnt, 1, __ATOMIC_RELAXED, __HIP_MEMORY_SCOPE_AGENT);
        int target = 128 * (tl + 1);
        while (__hip_atomic_load(cnt, __ATOMIC_RELAXED, __HIP_MEMORY_SCOPE_AGENT) < target)
          __builtin_amdgcn_s_sleep(2);
        __threadfence();
      }
      __syncthreads();
    }
  }
  c_st[bb * 1024 + u] = c;
}

// ---------------- attention ----------------
__global__ __launch_bounds__(256) void attn_k(const float* __restrict__ sent_enc,
                                              const float* __restrict__ qbuf,
                                              const int* __restrict__ words,
                                              float* __restrict__ attn_out,
                                              unsigned short* __restrict__ fH,
                                              unsigned short* __restrict__ fL) {
  int b = blockIdx.x >> 4;
  int i = blockIdx.x & 15;
  int tid = threadIdx.x;
  __shared__ float se[16][512];
  __shared__ float qq[16][512];
  __shared__ float sc[16][16];
  __shared__ int kv[16];
  if (tid < 16) kv[tid] = 0;
  __syncthreads();
  {
    int j = tid >> 4, c = tid & 15;
    if (words[(b * 16 + j) * 16 + c] != 0) atomicOr(&kv[j], 1);
  }
  for (int idx = tid; idx < 16 * 128; idx += 256) {
    int j = idx >> 7, d4 = idx & 127;
    *(float4*)&se[j][d4 * 4] = *(const float4*)(sent_enc + (long)(b * 16 + j) * 512 + d4 * 4);
  }
  for (int idx = tid; idx < 16 * 128; idx += 256) {
    int c = idx >> 7, d4 = idx & 127;
    *(float4*)&qq[c][d4 * 4] = *(const float4*)(qbuf + (long)(b * 256 + i * 16 + c) * 512 + d4 * 4);
  }
  __syncthreads();
  int c = tid >> 4, j = tid & 15;
  {
    float s = 0.f;
#pragma unroll 4
    for (int k = 0; k < 512; k++) s += qq[c][k] * se[j][k];
    bool valid = (kv[j] != 0) && (j != i);
    sc[c][j] = valid ? s : -1e9f;
  }
  __syncthreads();
  float m = -INFINITY;
#pragma unroll
  for (int t = 0; t < 16; t++) m = fmaxf(m, sc[c][t]);
  float den = 0.f;
#pragma unroll
  for (int t = 0; t < 16; t++) den += expf(sc[c][t] - m);
  float a = expf(sc[c][j] - m) / den;
  __syncthreads();
  sc[c][j] = a;
  attn_out[((long)((b * 16 + i) * 16 + c)) * 16 + j] = a;
  __syncthreads();
  {
    int part = tid & 15;
    int cc = tid >> 4;
    for (int d = part * 32; d < part * 32 + 32; d++) {
      float v = 0.f;
#pragma unroll
      for (int jj = 0; jj < 16; jj++) v += sc[cc][jj] * se[jj][d];
      long o = (long)(b * 256 + i * 16 + cc) * 1544 + d;
      unsigned short hh, hl;
      splitf(v, hh, hl);
      fH[o] = hh;
      fL[o] = hl;
    }
  }
}

// ---------------------------------------------------------------------------
extern "C" void kernel_launch(void* const* d_in, const int* in_sizes, int n_in,
                              void* d_out, int out_size, void* d_ws, size_t ws_size,
                              hipStream_t stream) {
  const int* sents = (const int*)d_in[0];
  const int* words = (const int*)d_in[1];
  const int* labels = (const int*)d_in[2];
  const float* word_embs = (const float*)d_in[3];
  const float* char_table = (const float*)d_in[4];
  const float* sent_Wx0 = (const float*)d_in[5];
  const float* sent_Wh0 = (const float*)d_in[6];
  const float* sent_b0 = (const float*)d_in[7];
  const float* sent_Wx1 = (const float*)d_in[8];
  const float* sent_Wh1 = (const float*)d_in[9];
  const float* sent_b1 = (const float*)d_in[10];
  const float* word_Wx0 = (const float*)d_in[11];
  const float* word_Wh0 = (const float*)d_in[12];
  const float* word_b0 = (const float*)d_in[13];
  const float* word_Wx1 = (const float*)d_in[14];
  const float* word_Wh1 = (const float*)d_in[15];
  const float* word_b1 = (const float*)d_in[16];
  const float* attn_Wq = (const float*)d_in[17];
  const float* dec_Wx = (const float*)d_in[18];
  const float* dec_Wh = (const float*)d_in[19];
  const float* dec_b = (const float*)d_in[20];
  const float* cls_W = (const float*)d_in[21];
  const float* cls_b = (const float*)d_in[22];

  char* base = (char*)d_ws;
  // ---- Slot Z (early phase; overlaid by WhF pairs during decoder) ---------
  float* wembs   = (float*)(base + 0);          // 153600 fl
  float* preS    = (float*)(base + 614400);     // 1048576 fl
  float* hs0     = (float*)(base + 4808704);    // 262144 fl
  float* WhT0    = (float*)(base + 5857280);    // 524288 fl
  float* WhT1    = (float*)(base + 7954432);    // 524288 fl
  float* sentenc = (float*)(base + 10051584);   // 262144 fl
  unsigned short* hcharH = (unsigned short*)(base + 11100160);  // 1048576 us
  unsigned short* hcharL = (unsigned short*)(base + 13197312);  // 1048576 us
  float* cchar   = (float*)(base + 15294464);   // 524288 fl  (Z ends 17391616)
  unsigned short* WhFH = (unsigned short*)(base + 0);        // 4194304 us (overlay)
  unsigned short* WhFL = (unsigned short*)(base + 8388608);  // 4194304 us
  // ---- Slot W: finalb pairs ----------------------------------------------
  unsigned short* finalbH = (unsigned short*)(base + 17391616);  // 12648448 us
  unsigned short* finalbL = (unsigned short*)(base + 42688512);  // 12648448 us
  // ---- Slot Y: q (attn) then pre-chunk (decoder), 4194304 fl --------------
  float* qbuf = (float*)(base + 67985408);
  float* pre  = qbuf;
  // ---- WqT ----------------------------------------------------------------
  float* WqT = (float*)(base + 84762624);       // 524288 fl
  // ---- Slot X (char phase; overlaid by decoder/classifier buffers) --------
  unsigned short* charinH = (unsigned short*)(base + 86859776);   // 4456448 us
  unsigned short* charinL = (unsigned short*)(base + 95772672);   // 4456448 us
  unsigned short* hc0H = (unsigned short*)(base + 104685568);     // 8388608 us
  unsigned short* hc0L = (unsigned short*)(base + 121462784);     // 8388608 us (X ends 138240000)
  float* dec_out = (float*)(base + 86859776);                     // 8388608 fl (overlay)
  unsigned short* hdecH = (unsigned short*)(base + 120414208);    // 65536 us
  unsigned short* hdecL = (unsigned short*)(base + 120545280);    // 65536 us
  float* c_dec = (float*)(base + 120676352);                      // 32768 fl
  float* clsWT = (float*)(base + 120807424);                      // 15360 fl
  int* cnt = (int*)(base + 120868864);

  float* dout = (float*)d_out;
  float* diac = dout;              // 8192 x 15
  float* attnmap = dout + 122880;  // 32 x 16 x 16 x 16

  // ---- weight preprocessing (sentence + attention) --------------------------
  transpose_k<<<dim3(32, 8), 256, 0, stream>>>(sent_Wh0, WhT0, 1024, 256, 0);
  transpose_k<<<dim3(32, 8), 256, 0, stream>>>(sent_Wh0 + 262144, WhT0 + 262144, 1024, 256, 0);
  transpose_k<<<dim3(32, 8), 256, 0, stream>>>(sent_Wh1, WhT1, 1024, 256, 0);
  transpose_k<<<dim3(32, 8), 256, 0, stream>>>(sent_Wh1 + 262144, WhT1 + 262144, 1024, 256, 0);
  transpose_k<<<dim3(32, 16), 256, 0, stream>>>(attn_Wq, WqT, 1024, 512, 0);

  // ---- sentence encoder -----------------------------------------------------
  embed_k<<<600, 256, 0, stream>>>(sents, word_embs, wembs);
  gemm_k<1><<<dim3(8, 32), 256, 0, stream>>>(wembs, 300, sent_Wx0, sent_b0,
                                             preS, 2048, 512, 2048, 300);
  sent_rec_k<<<64, 256, 0, stream>>>(preS, WhT0, hs0);
  gemm_k<1><<<dim3(8, 32), 256, 0, stream>>>(hs0, 512, sent_Wx1, sent_b1,
                                             preS, 2048, 512, 2048, 512);
  sent_rec_k<<<64, 256, 0, stream>>>(preS, WhT1, sentenc);

  // ---- char encoder ---------------------------------------------------------
  charin_k<<<17408, 256, 0, stream>>>(words, char_table, sentenc, charinH, charinL);

  hipMemsetAsync(base + 11100160, 0, 6291456, stream);  // hcharH/L + cchar
  for (int s = 0; s < 16; s++) {
    int p = s & 1;
    mstep_k<544><<<dim3(8, 64), 256, 0, stream>>>(
        charinH + s * 544, charinL + s * 544,
        charinH + (15 - s) * 544, charinL + (15 - s) * 544, 16 * 544,
        word_Wx0, word_Wh0, word_b0,
        hcharH + p * 524288, hcharL + p * 524288,
        hcharH + (p ^ 1) * 524288, hcharL + (p ^ 1) * 524288, cchar,
        hc0H, hc0L, 1024, s, 15 - s);
  }
  hipMemsetAsync(base + 11100160, 0, 6291456, stream);
  for (int s = 0; s < 16; s++) {
    int p = s & 1;
    mstep_k<1024><<<dim3(8, 64), 256, 0, stream>>>(
        hc0H + s * 1024, hc0L + s * 1024,
        hc0H + (15 - s) * 1024, hc0L + (15 - s) * 1024, 16 * 1024,
        word_Wx1, word_Wh1, word_b1,
        hcharH + p * 524288, hcharL + p * 524288,
        hcharH + (p ^ 1) * 524288, hcharL + (p ^ 1) * 524288, cchar,
        finalbH + 512, finalbL + 512, 1544, s, 15 - s);
  }

  // ---- attention ------------------------------------------------------------
  mgemm_k<0, 0, 0><<<dim3(128, 8), 256, 0, stream>>>(finalbH + 512, finalbL + 512, 1544, 0,
                                                     WqT, nullptr, qbuf, 512, 1024);
  attn_k<<<512, 256, 0, stream>>>(sentenc, qbuf, words, attnmap, finalbH, finalbL);
  labels_k<<<256, 256, 0, stream>>>(labels, finalbH, finalbL);

  // ---- decoder --------------------------------------------------------------
  decwh_prep_k<<<16384, 256, 0, stream>>>(dec_Wh, WhFH, WhFL);  // overlays Slot Z
  hipMemsetAsync(base + 120414208, 0, 393216, stream);          // hdecH/L + c_dec
  for (int ch = 0; ch < 8; ch++) {
    mgemm_k<1, 1024, 1><<<dim3(16, 64), 256, 0, stream>>>(finalbH, finalbL, 1544, ch * 32,
                                                          dec_Wx, dec_b, pre, 4096, 1544);
    hipMemsetAsync(cnt, 0, 256, stream);
    dec_persist_k<<<128, 256, 0, stream>>>(WhFH, WhFL, pre, hdecH, hdecL,
                                           c_dec, dec_out, cnt, ch * 32);
  }

  // ---- classifier -----------------------------------------------------------
  transpose_k<<<dim3(32, 1), 256, 0, stream>>>(cls_W, clsWT, 1024, 15, 0);
  gemm_k<1><<<dim3(128, 1), 256, 0, stream>>>(dec_out, 1024, clsWT, cls_b,
                                              diac, 15, 8192, 15, 1024);
}

// Round 5
// 7316.780 us; speedup vs baseline: 2.5655x; 1.0363x over previous
//
#include <hip/hip_runtime.h>
#include <math.h>

// ---------------------------------------------------------------------------
// DiacritizerD3: split-bf16 MFMA pipeline, persistent decoder w/ asm-pinned
// register-resident weights + 2-level grid barrier.
// B=32, TS=16, TW=16, SENT_H=256 (DIN=512), WORD_H=512 (DQ=DEC_H=1024),
// CDIM=32, WDIM=300, DEC_IN=1544.
// ---------------------------------------------------------------------------

typedef __attribute__((ext_vector_type(8))) __bf16 bf16x8;
typedef __attribute__((ext_vector_type(4))) float f32x4;
typedef __attribute__((ext_vector_type(4))) unsigned u32x4;

__device__ __forceinline__ float sigf(float x) { return 1.0f / (1.0f + expf(-x)); }

__device__ __forceinline__ unsigned short bf16rn(float x) {
  unsigned u = __float_as_uint(x);
  return (unsigned short)((u + 0x7fffu + ((u >> 16) & 1u)) >> 16);
}
__device__ __forceinline__ void splitf(float x, unsigned short& h, unsigned short& l) {
  h = bf16rn(x);
  float fh = __uint_as_float((unsigned)h << 16);
  l = bf16rn(x - fh);
}

#define FMA16(a, b, acc)                                                           \
  acc[0][0] += a.x * b.x; acc[0][1] += a.x * b.y; acc[0][2] += a.x * b.z; acc[0][3] += a.x * b.w; \
  acc[1][0] += a.y * b.x; acc[1][1] += a.y * b.y; acc[1][2] += a.y * b.z; acc[1][3] += a.y * b.w; \
  acc[2][0] += a.z * b.x; acc[2][1] += a.z * b.y; acc[2][2] += a.z * b.z; acc[2][3] += a.z * b.w; \
  acc[3][0] += a.w * b.x; acc[3][1] += a.w * b.y; acc[3][2] += a.w * b.z; acc[3][3] += a.w * b.w;

// ---------------- transpose ----------------
__global__ __launch_bounds__(256) void transpose_k(const float* __restrict__ in,
                                                   float* __restrict__ out,
                                                   int R, int C, int H) {
  __shared__ float tile[32][33];
  int r0 = blockIdx.x * 32, c0 = blockIdx.y * 32;
  int tx = threadIdx.x & 31, ty = threadIdx.x >> 5;
  for (int yy = ty; yy < 32; yy += 8) {
    int r = r0 + yy, c = c0 + tx;
    float v = 0.f;
    if (r < R && c < C) {
      int gs = H ? ((r & 3) * H + (r >> 2)) : r;
      v = in[(long)gs * C + c];
    }
    tile[yy][tx] = v;
  }
  __syncthreads();
  for (int yy = ty; yy < 32; yy += 8) {
    int c = c0 + yy, r = r0 + tx;
    if (r < R && c < C) out[(long)c * R + r] = tile[tx][yy];
  }
}

// ---------------- embedding lookup ----------------
__global__ void embed_k(const int* __restrict__ sents, const float* __restrict__ word_embs,
                        float* __restrict__ wembs) {
  int idx = blockIdx.x * 256 + threadIdx.x;
  if (idx >= 512 * 300) return;
  int r = idx / 300, k = idx - r * 300;
  wembs[idx] = word_embs[(long)sents[r] * 300 + k];
}

// ---------------- char-encoder input build (writes bf16 hi/lo pairs) --------
__global__ void charin_k(const int* __restrict__ words, const float* __restrict__ char_table,
                         const float* __restrict__ sent_enc,
                         unsigned short* __restrict__ ciH, unsigned short* __restrict__ ciL) {
  int idx = blockIdx.x * 256 + threadIdx.x;
  if (idx >= 512 * 16 * 544) return;
  int k = idx % 544;
  int rc = idx / 544;
  int c = rc & 15, n = rc >> 4;
  int w = words[n * 16 + c];
  float v;
  if (k < 32) v = char_table[w * 32 + k];
  else v = (w != 0) ? sent_enc[n * 512 + (k - 32)] : 0.f;
  unsigned short h, l;
  splitf(v, h, l);
  ciH[idx] = h; ciL[idx] = l;
}

// ---------------- labels -> final[:,1536:1544] (pairs) ----------------------
__global__ void labels_k(const int* __restrict__ labels,
                         unsigned short* __restrict__ fH, unsigned short* __restrict__ fL) {
  int idx = blockIdx.x * 256 + threadIdx.x;
  if (idx >= 8192 * 8) return;
  int r = idx >> 3, l = idx & 7;
  long o = (long)r * 1544 + 1536 + l;
  fH[o] = bf16rn((float)labels[idx]);
  fL[o] = 0;
}

// ---------------- dec_Wh -> fragment-contiguous split layout ----------------
// WhF[nt][kt][lane][8]: col = nt*16+(lane&15) (unit-major), k = kt*32+((lane>>4)&3)*8+j
__global__ void decwh_prep_k(const float* __restrict__ dec_Wh,
                             unsigned short* __restrict__ WhFH,
                             unsigned short* __restrict__ WhFL) {
  long o = (long)blockIdx.x * 256 + threadIdx.x;
  if (o >= 4194304) return;
  int j = (int)(o & 7);
  int lane = (int)((o >> 3) & 63);
  int kt = (int)((o >> 9) & 31);
  int nt = (int)(o >> 14);
  int col = nt * 16 + (lane & 15);
  int gsrc = (col & 3) * 1024 + (col >> 2);
  int k = kt * 32 + ((lane >> 4) & 3) * 8 + j;
  float v = dec_Wh[(long)gsrc * 1024 + k];
  unsigned short h, l;
  splitf(v, h, l);
  WhFH[o] = h; WhFL[o] = l;
}

// ---------------- fp32 fallback GEMM (sentence Wx, classifier) --------------
template <int HASBIAS>
__global__ __launch_bounds__(256) void gemm_k(const float* __restrict__ A, int lda,
                                              const float* __restrict__ Bw,
                                              const float* __restrict__ bias,
                                              float* __restrict__ C, int ldc,
                                              int M, int N, int K) {
  __shared__ float As[32][64];
  __shared__ float Bs[32][64];
  int tid = threadIdx.x;
  int m0 = blockIdx.x * 64, n0 = blockIdx.y * 64;
  int tn = tid & 15, tm = tid >> 4;
  int lrow = tid >> 2, lk = (tid & 3) * 8;
  float acc[4][4] = {};
  int am = m0 + lrow;
  const float* aptr = A + (long)am * lda;
  bool mok = am < M;
  int bn = n0 + lrow;
  const float* bptr = Bw + (long)bn * K;
  bool nok = bn < N;

  for (int k0 = 0; k0 < K; k0 += 32) {
    int kb = k0 + lk;
    if (kb + 8 <= K) {
      if (mok) {
        float4 v0 = *(const float4*)(aptr + kb);
        float4 v1 = *(const float4*)(aptr + kb + 4);
        As[lk + 0][lrow] = v0.x; As[lk + 1][lrow] = v0.y; As[lk + 2][lrow] = v0.z; As[lk + 3][lrow] = v0.w;
        As[lk + 4][lrow] = v1.x; As[lk + 5][lrow] = v1.y; As[lk + 6][lrow] = v1.z; As[lk + 7][lrow] = v1.w;
      } else {
#pragma unroll
        for (int i = 0; i < 8; i++) As[lk + i][lrow] = 0.f;
      }
      if (nok) {
        float4 v0 = *(const float4*)(bptr + kb);
        float4 v1 = *(const float4*)(bptr + kb + 4);
        Bs[lk + 0][lrow] = v0.x; Bs[lk + 1][lrow] = v0.y; Bs[lk + 2][lrow] = v0.z; Bs[lk + 3][lrow] = v0.w;
        Bs[lk + 4][lrow] = v1.x; Bs[lk + 5][lrow] = v1.y; Bs[lk + 6][lrow] = v1.z; Bs[lk + 7][lrow] = v1.w;
      } else {
#pragma unroll
        for (int i = 0; i < 8; i++) Bs[lk + i][lrow] = 0.f;
      }
    } else {
#pragma unroll
      for (int i = 0; i < 8; i++) {
        int k = kb + i;
        As[lk + i][lrow] = (mok && k < K) ? aptr[k] : 0.f;
        Bs[lk + i][lrow] = (nok && k < K) ? bptr[k] : 0.f;
      }
    }
    __syncthreads();
#pragma unroll
    for (int kk = 0; kk < 32; kk++) {
      float4 a = *(const float4*)&As[kk][tm * 4];
      float4 b = *(const float4*)&Bs[kk][tn * 4];
      FMA16(a, b, acc)
    }
    __syncthreads();
  }
#pragma unroll
  for (int i = 0; i < 4; i++) {
    int m = m0 + tm * 4 + i;
    if (m >= M) continue;
#pragma unroll
    for (int j = 0; j < 4; j++) {
      int n = n0 + tn * 4 + j;
      if (n >= N) continue;
      float v = acc[i][j];
      if (HASBIAS) v += bias[n];
      C[(long)m * ldc + n] = v;
    }
  }
}

// ---------------- split-bf16 MFMA GEMM, pre-split A: C = A * B^T (+bias) ----
template <int AMODE, int BH, int HASBIAS>
__global__ __launch_bounds__(256) void mgemm_k(const unsigned short* __restrict__ AH,
                                               const unsigned short* __restrict__ AL,
                                               int lda, int at0,
                                               const float* __restrict__ B,
                                               const float* __restrict__ bias,
                                               float* __restrict__ C, int ldc, int K) {
  __shared__ __align__(16) unsigned short Ah[64 * 40], Al[64 * 40], Bh[64 * 40], Bl[64 * 40];
  int tid = threadIdx.x;
  int m0 = blockIdx.x * 64, n0 = blockIdx.y * 64;
  int srow = tid >> 2, skoff = (tid & 3) * 8;
  int am = m0 + srow;
  long arow = (AMODE == 1) ? ((long)(am & 31) * 256 + at0 + (am >> 5)) : (long)am;
  const unsigned short* aptrH = AH + arow * (long)lda;
  const unsigned short* aptrL = AL + arow * (long)lda;
  int bn = n0 + srow;
  long gsrc;
  if (BH > 0) gsrc = (long)(bn & 3) * BH + (bn >> 2);
  else gsrc = bn;
  const float* bptr = B + gsrc * (long)K;

  int lane = tid & 63, wv = tid >> 6;
  int wm = (wv >> 1) * 32, wn = (wv & 1) * 32;
  int fr = lane & 15, fk = (lane >> 4) * 8;
  int rbase = (lane >> 4) * 4;

  f32x4 acc[2][2] = {};
  for (int k0 = 0; k0 < K; k0 += 32) {
    int kb = k0 + skoff;
    uint4 vh, vl;
    unsigned short hb[8] __attribute__((aligned(16))), lb[8] __attribute__((aligned(16)));
    if (kb + 8 <= K) {
      vh = *(const uint4*)(aptrH + kb);
      vl = *(const uint4*)(aptrL + kb);
      float4 b0 = *(const float4*)(bptr + kb);
      float4 b1 = *(const float4*)(bptr + kb + 4);
      float bv[8] = {b0.x, b0.y, b0.z, b0.w, b1.x, b1.y, b1.z, b1.w};
#pragma unroll
      for (int e = 0; e < 8; e++) splitf(bv[e], hb[e], lb[e]);
    } else {
      unsigned short ea[8] __attribute__((aligned(16))), el[8] __attribute__((aligned(16)));
#pragma unroll
      for (int e = 0; e < 8; e++) {
        int k = kb + e;
        ea[e] = (k < K) ? aptrH[k] : 0;
        el[e] = (k < K) ? aptrL[k] : 0;
        float bvv = (k < K) ? bptr[k] : 0.f;
        splitf(bvv, hb[e], lb[e]);
      }
      vh = *(const uint4*)ea;
      vl = *(const uint4*)el;
    }
    __syncthreads();
    *(uint4*)&Ah[srow * 40 + skoff] = vh;
    *(uint4*)&Al[srow * 40 + skoff] = vl;
    *(uint4*)&Bh[srow * 40 + skoff] = *(const uint4*)hb;
    *(uint4*)&Bl[srow * 40 + skoff] = *(const uint4*)lb;
    __syncthreads();
    bf16x8 fah[2], fal[2], fbh[2], fbl[2];
#pragma unroll
    for (int i = 0; i < 2; i++) {
      fah[i] = *(const bf16x8*)&Ah[(wm + i * 16 + fr) * 40 + fk];
      fal[i] = *(const bf16x8*)&Al[(wm + i * 16 + fr) * 40 + fk];
      fbh[i] = *(const bf16x8*)&Bh[(wn + i * 16 + fr) * 40 + fk];
      fbl[i] = *(const bf16x8*)&Bl[(wn + i * 16 + fr) * 40 + fk];
    }
#pragma unroll
    for (int i = 0; i < 2; i++)
#pragma unroll
      for (int j = 0; j < 2; j++) {
        acc[i][j] = __builtin_amdgcn_mfma_f32_16x16x32_bf16(fah[i], fbh[j], acc[i][j], 0, 0, 0);
        acc[i][j] = __builtin_amdgcn_mfma_f32_16x16x32_bf16(fah[i], fbl[j], acc[i][j], 0, 0, 0);
        acc[i][j] = __builtin_amdgcn_mfma_f32_16x16x32_bf16(fal[i], fbh[j], acc[i][j], 0, 0, 0);
      }
  }
#pragma unroll
  for (int i = 0; i < 2; i++)
#pragma unroll
    for (int j = 0; j < 2; j++)
#pragma unroll
      for (int r = 0; r < 4; r++) {
        int m = m0 + wm + i * 16 + rbase + r;
        int n = n0 + wn + j * 16 + fr;
        float v = acc[i][j][r];
        if (HASBIAS) {
          long gs = (BH > 0) ? ((long)(n & 3) * BH + (n >> 2)) : (long)n;
          v += bias[gs];
        }
        C[(long)m * ldc + n] = v;
      }
}

// ---------------- char-encoder fused step (pre-split A, MFMA, LSTM cell) ----
template <int K1>
__global__ __launch_bounds__(256) void mstep_k(
    const unsigned short* __restrict__ xFH, const unsigned short* __restrict__ xFL,
    const unsigned short* __restrict__ xBH, const unsigned short* __restrict__ xBL,
    int xstride,
    const float* __restrict__ Wx, const float* __restrict__ Wh,
    const float* __restrict__ bias,
    const unsigned short* __restrict__ hInH, const unsigned short* __restrict__ hInL,
    unsigned short* __restrict__ hOutH, unsigned short* __restrict__ hOutL,
    float* __restrict__ c_st,
    unsigned short* __restrict__ outH, unsigned short* __restrict__ outL,
    int out_stride, int tF, int tB) {
  __shared__ __align__(16) char smem[20480];
  unsigned short* Ah = (unsigned short*)smem;
  unsigned short* Al = Ah + 2560;
  unsigned short* Bh = Ah + 5120;
  unsigned short* Bl = Ah + 7680;
  float* gbuf = (float*)smem;  // [64][68] after MFMA loop (17408 B)

  int tid = threadIdx.x;
  int m0 = blockIdx.x * 64, n0 = blockIdx.y * 64;
  int dir = n0 >> 11;
  int nn0 = n0 & 2047;
  int srow = tid >> 2, skoff = (tid & 3) * 8;

  int am = m0 + srow;
  const unsigned short* axH = dir ? xBH : xFH;
  const unsigned short* axL = dir ? xBL : xFL;
  const unsigned short* arow_xH = axH + (long)am * xstride;
  const unsigned short* arow_xL = axL + (long)am * xstride;
  const unsigned short* arow_hH = hInH + (long)dir * 262144 + (long)am * 512;
  const unsigned short* arow_hL = hInL + (long)dir * 262144 + (long)am * 512;

  int bn = nn0 + srow;
  long gsrc = (long)dir * 2048 + (bn & 3) * 512 + (bn >> 2);
  const float* brow_x = Wx + gsrc * (long)K1;
  const float* brow_h = Wh + gsrc * 512L;

  int lane = tid & 63, wv = tid >> 6;
  int wm = (wv >> 1) * 32, wn = (wv & 1) * 32;
  int fr = lane & 15, fk = (lane >> 4) * 8;
  int rbase = (lane >> 4) * 4;

  f32x4 acc[2][2] = {};
  const int K = K1 + 512;
  for (int k0 = 0; k0 < K; k0 += 32) {
    int kb = k0 + skoff;
    uint4 vh, vl;
    const float* bp;
    if (kb < K1) {
      vh = *(const uint4*)(arow_xH + kb);
      vl = *(const uint4*)(arow_xL + kb);
      bp = brow_x + kb;
    } else {
      vh = *(const uint4*)(arow_hH + (kb - K1));
      vl = *(const uint4*)(arow_hL + (kb - K1));
      bp = brow_h + (kb - K1);
    }
    float4 b0 = *(const float4*)bp;
    float4 b1 = *(const float4*)(bp + 4);
    float bv[8] = {b0.x, b0.y, b0.z, b0.w, b1.x, b1.y, b1.z, b1.w};
    unsigned short hb[8] __attribute__((aligned(16))), lb[8] __attribute__((aligned(16)));
#pragma unroll
    for (int e = 0; e < 8; e++) splitf(bv[e], hb[e], lb[e]);
    __syncthreads();
    *(uint4*)&Ah[srow * 40 + skoff] = vh;
    *(uint4*)&Al[srow * 40 + skoff] = vl;
    *(uint4*)&Bh[srow * 40 + skoff] = *(const uint4*)hb;
    *(uint4*)&Bl[srow * 40 + skoff] = *(const uint4*)lb;
    __syncthreads();
    bf16x8 fah[2], fal[2], fbh[2], fbl[2];
#pragma unroll
    for (int i = 0; i < 2; i++) {
      fah[i] = *(const bf16x8*)&Ah[(wm + i * 16 + fr) * 40 + fk];
      fal[i] = *(const bf16x8*)&Al[(wm + i * 16 + fr) * 40 + fk];
      fbh[i] = *(const bf16x8*)&Bh[(wn + i * 16 + fr) * 40 + fk];
      fbl[i] = *(const bf16x8*)&Bl[(wn + i * 16 + fr) * 40 + fk];
    }
#pragma unroll
    for (int i = 0; i < 2; i++)
#pragma unroll
      for (int j = 0; j < 2; j++) {
        acc[i][j] = __builtin_amdgcn_mfma_f32_16x16x32_bf16(fah[i], fbh[j], acc[i][j], 0, 0, 0);
        acc[i][j] = __builtin_amdgcn_mfma_f32_16x16x32_bf16(fah[i], fbl[j], acc[i][j], 0, 0, 0);
        acc[i][j] = __builtin_amdgcn_mfma_f32_16x16x32_bf16(fal[i], fbh[j], acc[i][j], 0, 0, 0);
      }
  }
  __syncthreads();  // tiles dead; reuse LDS as gate buffer
#pragma unroll
  for (int i = 0; i < 2; i++)
#pragma unroll
    for (int j = 0; j < 2; j++)
#pragma unroll
      for (int r = 0; r < 4; r++)
        gbuf[(wm + i * 16 + rbase + r) * 68 + (wn + j * 16 + fr)] = acc[i][j][r];
  __syncthreads();

  int ug0 = nn0 >> 2;
  int t = dir ? tB : tF;
  for (int it = tid; it < 1024; it += 256) {
    int r = it >> 4, ul = it & 15;
    int seq = m0 + r, ug = ug0 + ul;
    float gi = gbuf[r * 68 + ul * 4 + 0] + bias[dir * 2048 + ug];
    float gf = gbuf[r * 68 + ul * 4 + 1] + bias[dir * 2048 + 512 + ug];
    float gg = gbuf[r * 68 + ul * 4 + 2] + bias[dir * 2048 + 1024 + ug];
    float go = gbuf[r * 68 + ul * 4 + 3] + bias[dir * 2048 + 1536 + ug];
    long ci = (long)dir * 262144 + (long)seq * 512 + ug;
    float c = sigf(gf) * c_st[ci] + sigf(gi) * tanhf(gg);
    float h = sigf(go) * tanhf(c);
    c_st[ci] = c;
    unsigned short hh, hl;
    splitf(h, hh, hl);
    hOutH[ci] = hh;
    hOutL[ci] = hl;
    long oo = ((long)seq * 16 + t) * out_stride + dir * 512 + ug;
    outH[oo] = hh;
    outL[oo] = hl;
  }
}

// ---------------- sentence recurrent ----------------
__global__ __launch_bounds__(256) void sent_rec_k(const float* __restrict__ pre,
                                                  const float* __restrict__ WhT,
                                                  float* __restrict__ out) {
  int blk = blockIdx.x;
  int n = blk & 31, dir = blk >> 5;
  int tid = threadIdx.x;
  __shared__ float hls[256];
  __shared__ float gls[1024];
  float c = 0.f;
  hls[tid] = 0.f;
  __syncthreads();
  const float* whbase = WhT + (long)dir * 256 * 1024;
  int g4 = tid * 4;
  for (int s = 0; s < 16; s++) {
    int t = dir ? (15 - s) : s;
    const float* prow = pre + (long)(n * 16 + t) * 2048 + dir * 1024;
    float ax = 0.f, ay = 0.f, az = 0.f, aw = 0.f;
#pragma unroll 4
    for (int k = 0; k < 256; k++) {
      float hk = hls[k];
      float4 w = *(const float4*)(whbase + (long)k * 1024 + g4);
      ax += hk * w.x; ay += hk * w.y; az += hk * w.z; aw += hk * w.w;
    }
    float4 p = *(const float4*)(prow + g4);
    gls[g4 + 0] = ax + p.x; gls[g4 + 1] = ay + p.y;
    gls[g4 + 2] = az + p.z; gls[g4 + 3] = aw + p.w;
    __syncthreads();
    float gi = gls[tid], gf = gls[256 + tid], gg = gls[512 + tid], go = gls[768 + tid];
    c = sigf(gf) * c + sigf(gi) * tanhf(gg);
    float h = sigf(go) * tanhf(c);
    __syncthreads();
    hls[tid] = h;
    out[(long)n * 8192 + (long)t * 512 + dir * 256 + tid] = h;
    __syncthreads();
  }
}

// ---------------- persistent decoder: 32 steps, asm-pinned weights ----------
// 128 blocks x 256 thr. Block bid: gate-cols [bid*32, bid*32+32) (units
// bid*8..+8), all 32 batches. Waves: nh = wv&1 (16-col half), kh = wv>>1
// (512-K half). Weights live in 128 VGPRs pinned with asm (compiler sank
// them in R4: VGPR_Count was 96 < the 128 needed — every step re-loaded
// through the fence-invalidated L2). 2-level barrier: 16 group counters +
// root (was: 128 serialized RMWs on one line).
__global__ __launch_bounds__(256, 1) void dec_persist_k(
    const unsigned short* __restrict__ WhFH, const unsigned short* __restrict__ WhFL,
    const float* __restrict__ pre,
    unsigned short* __restrict__ hH, unsigned short* __restrict__ hL,
    float* __restrict__ c_st, float* __restrict__ dec_out,
    int* __restrict__ cnt, int tbase) {
  __shared__ float gbuf[2][32][33];
  int tid = threadIdx.x, bid = blockIdx.x;
  int lane = tid & 63, wv = tid >> 6;
  int nh = wv & 1, kh = wv >> 1;
  int fr = lane & 15, fq = (lane >> 4) & 3;

  // weight preload into registers: nt = bid*2+nh, kt = kh*16+i
  u32x4 wHr[16], wLr[16];
  {
    long wbase = ((long)(bid * 2 + nh) * 32 + kh * 16) * 512 + lane * 8;
#pragma unroll
    for (int i = 0; i < 16; i++) {
      wHr[i] = *(const u32x4*)&WhFH[wbase + i * 512];
      wLr[i] = *(const u32x4*)&WhFL[wbase + i * 512];
    }
  }
#pragma unroll
  for (int i = 0; i < 16; i++)
    asm volatile("" : "+v"(wHr[i]), "+v"(wLr[i]));  // pin: opaque RW, no sink/remat

  // cell mapping: one thread per (batch bb, unit-local ul)
  int ul = tid & 7, bb = tid >> 3;
  int u = bid * 8 + ul;
  float c = c_st[bb * 1024 + u];
  int grp = bid >> 3;  // 16 groups of 8 blocks

  for (int tl = 0; tl < 32; tl++) {
    int t = tbase + tl;
    const unsigned short* hInH = hH + (long)(t & 1) * 32768;
    const unsigned short* hInL = hL + (long)(t & 1) * 32768;
    unsigned short* hOutH = hH + (long)((t + 1) & 1) * 32768;
    unsigned short* hOutL = hL + (long)((t + 1) & 1) * 32768;
    f32x4 acc0 = {0.f, 0.f, 0.f, 0.f};  // batches 0..15
    f32x4 acc1 = {0.f, 0.f, 0.f, 0.f};  // batches 16..31
#pragma unroll
    for (int i = 0; i < 16; i++) {
      int k = (kh * 16 + i) * 32 + fq * 8;
      long a0 = (long)fr * 1024 + k;
      long a1 = (long)(16 + fr) * 1024 + k;
      bf16x8 ah0 = *(const bf16x8*)&hInH[a0];
      bf16x8 al0 = *(const bf16x8*)&hInL[a0];
      bf16x8 ah1 = *(const bf16x8*)&hInH[a1];
      bf16x8 al1 = *(const bf16x8*)&hInL[a1];
      bf16x8 wh = __builtin_bit_cast(bf16x8, wHr[i]);
      bf16x8 wl = __builtin_bit_cast(bf16x8, wLr[i]);
      acc0 = __builtin_amdgcn_mfma_f32_16x16x32_bf16(ah0, wh, acc0, 0, 0, 0);
      acc1 = __builtin_amdgcn_mfma_f32_16x16x32_bf16(ah1, wh, acc1, 0, 0, 0);
      acc0 = __builtin_amdgcn_mfma_f32_16x16x32_bf16(ah0, wl, acc0, 0, 0, 0);
      acc1 = __builtin_amdgcn_mfma_f32_16x16x32_bf16(ah1, wl, acc1, 0, 0, 0);
      acc0 = __builtin_amdgcn_mfma_f32_16x16x32_bf16(al0, wh, acc0, 0, 0, 0);
      acc1 = __builtin_amdgcn_mfma_f32_16x16x32_bf16(al1, wh, acc1, 0, 0, 0);
    }
#pragma unroll
    for (int r = 0; r < 4; r++) {
      gbuf[kh][fq * 4 + r][nh * 16 + fr] = acc0[r];
      gbuf[kh][16 + fq * 4 + r][nh * 16 + fr] = acc1[r];
    }
    __syncthreads();
    {
      const float* pr = pre + ((long)tl * 32 + bb) * 4096 + bid * 32 + ul * 4;
      float4 p = *(const float4*)pr;
      float gi = gbuf[0][bb][ul * 4 + 0] + gbuf[1][bb][ul * 4 + 0] + p.x;
      float gf = gbuf[0][bb][ul * 4 + 1] + gbuf[1][bb][ul * 4 + 1] + p.y;
      float gg = gbuf[0][bb][ul * 4 + 2] + gbuf[1][bb][ul * 4 + 2] + p.z;
      float go = gbuf[0][bb][ul * 4 + 3] + gbuf[1][bb][ul * 4 + 3] + p.w;
      c = sigf(gf) * c + sigf(gi) * tanhf(gg);
      float h = sigf(go) * tanhf(c);
      unsigned short hh, hl;
      splitf(h, hh, hl);
      hOutH[bb * 1024 + u] = hh;
      hOutL[bb * 1024 + u] = hl;
      dec_out[((long)bb * 256 + t) * 1024 + u] = h;
    }
    __syncthreads();  // gbuf safe for next iter
    if (tl < 31) {
      if (tid == 0) {
        __threadfence();
        int old = __hip_atomic_fetch_add(&cnt[grp * 32], 1, __ATOMIC_RELAXED,
                                         __HIP_MEMORY_SCOPE_AGENT);
        if (old == 8 * tl + 7)  // last arriver of this group signals root
          __hip_atomic_fetch_add(&cnt[512], 1, __ATOMIC_RELAXED,
                                 __HIP_MEMORY_SCOPE_AGENT);
        while (__hip_atomic_load(&cnt[512], __ATOMIC_RELAXED,
                                 __HIP_MEMORY_SCOPE_AGENT) < 16 * (tl + 1))
          __builtin_amdgcn_s_sleep(4);
        __threadfence();
      }
      __syncthreads();
    }
  }
  c_st[bb * 1024 + u] = c;
}

// ---------------- attention ----------------
__global__ __launch_bounds__(256) void attn_k(const float* __restrict__ sent_enc,
                                              const float* __restrict__ qbuf,
                                              const int* __restrict__ words,
                                              float* __restrict__ attn_out,
                                              unsigned short* __restrict__ fH,
                                              unsigned short* __restrict__ fL) {
  int b = blockIdx.x >> 4;
  int i = blockIdx.x & 15;
  int tid = threadIdx.x;
  __shared__ float se[16][512];
  __shared__ float qq[16][512];
  __shared__ float sc[16][16];
  __shared__ int kv[16];
  if (tid < 16) kv[tid] = 0;
  __syncthreads();
  {
    int j = tid >> 4, c = tid & 15;
    if (words[(b * 16 + j) * 16 + c] != 0) atomicOr(&kv[j], 1);
  }
  for (int idx = tid; idx < 16 * 128; idx += 256) {
    int j = idx >> 7, d4 = idx & 127;
    *(float4*)&se[j][d4 * 4] = *(const float4*)(sent_enc + (long)(b * 16 + j) * 512 + d4 * 4);
  }
  for (int idx = tid; idx < 16 * 128; idx += 256) {
    int c = idx >> 7, d4 = idx & 127;
    *(float4*)&qq[c][d4 * 4] = *(const float4*)(qbuf + (long)(b * 256 + i * 16 + c) * 512 + d4 * 4);
  }
  __syncthreads();
  int c = tid >> 4, j = tid & 15;
  {
    float s = 0.f;
#pragma unroll 4
    for (int k = 0; k < 512; k++) s += qq[c][k] * se[j][k];
    bool valid = (kv[j] != 0) && (j != i);
    sc[c][j] = valid ? s : -1e9f;
  }
  __syncthreads();
  float m = -INFINITY;
#pragma unroll
  for (int t = 0; t < 16; t++) m = fmaxf(m, sc[c][t]);
  float den = 0.f;
#pragma unroll
  for (int t = 0; t < 16; t++) den += expf(sc[c][t] - m);
  float a = expf(sc[c][j] - m) / den;
  __syncthreads();
  sc[c][j] = a;
  attn_out[((long)((b * 16 + i) * 16 + c)) * 16 + j] = a;
  __syncthreads();
  {
    int part = tid & 15;
    int cc = tid >> 4;
    for (int d = part * 32; d < part * 32 + 32; d++) {
      float v = 0.f;
#pragma unroll
      for (int jj = 0; jj < 16; jj++) v += sc[cc][jj] * se[jj][d];
      long o = (long)(b * 256 + i * 16 + cc) * 1544 + d;
      unsigned short hh, hl;
      splitf(v, hh, hl);
      fH[o] = hh;
      fL[o] = hl;
    }
  }
}

// ---------------------------------------------------------------------------
extern "C" void kernel_launch(void* const* d_in, const int* in_sizes, int n_in,
                              void* d_out, int out_size, void* d_ws, size_t ws_size,
                              hipStream_t stream) {
  const int* sents = (const int*)d_in[0];
  const int* words = (const int*)d_in[1];
  const int* labels = (const int*)d_in[2];
  const float* word_embs = (const float*)d_in[3];
  const float* char_table = (const float*)d_in[4];
  const float* sent_Wx0 = (const float*)d_in[5];
  const float* sent_Wh0 = (const float*)d_in[6];
  const float* sent_b0 = (const float*)d_in[7];
  const float* sent_Wx1 = (const float*)d_in[8];
  const float* sent_Wh1 = (const float*)d_in[9];
  const float* sent_b1 = (const float*)d_in[10];
  const float* word_Wx0 = (const float*)d_in[11];
  const float* word_Wh0 = (const float*)d_in[12];
  const float* word_b0 = (const float*)d_in[13];
  const float* word_Wx1 = (const float*)d_in[14];
  const float* word_Wh1 = (const float*)d_in[15];
  const float* word_b1 = (const float*)d_in[16];
  const float* attn_Wq = (const float*)d_in[17];
  const float* dec_Wx = (const float*)d_in[18];
  const float* dec_Wh = (const float*)d_in[19];
  const float* dec_b = (const float*)d_in[20];
  const float* cls_W = (const float*)d_in[21];
  const float* cls_b = (const float*)d_in[22];

  char* base = (char*)d_ws;
  // ---- Slot Z (early phase; overlaid by WhF pairs during decoder) ---------
  float* wembs   = (float*)(base + 0);          // 153600 fl
  float* preS    = (float*)(base + 614400);     // 1048576 fl
  float* hs0     = (float*)(base + 4808704);    // 262144 fl
  float* WhT0    = (float*)(base + 5857280);    // 524288 fl
  float* WhT1    = (float*)(base + 7954432);    // 524288 fl
  float* sentenc = (float*)(base + 10051584);   // 262144 fl
  unsigned short* hcharH = (unsigned short*)(base + 11100160);  // 1048576 us
  unsigned short* hcharL = (unsigned short*)(base + 13197312);  // 1048576 us
  float* cchar   = (float*)(base + 15294464);   // 524288 fl  (Z ends 17391616)
  unsigned short* WhFH = (unsigned short*)(base + 0);        // 4194304 us (overlay)
  unsigned short* WhFL = (unsigned short*)(base + 8388608);  // 4194304 us
  // ---- Slot W: finalb pairs ----------------------------------------------
  unsigned short* finalbH = (unsigned short*)(base + 17391616);  // 12648448 us
  unsigned short* finalbL = (unsigned short*)(base + 42688512);  // 12648448 us
  // ---- Slot Y: q (attn) then pre-chunk (decoder), 4194304 fl --------------
  float* qbuf = (float*)(base + 67985408);
  float* pre  = qbuf;
  // ---- WqT ----------------------------------------------------------------
  float* WqT = (float*)(base + 84762624);       // 524288 fl
  // ---- Slot X (char phase; overlaid by decoder/classifier buffers) --------
  unsigned short* charinH = (unsigned short*)(base + 86859776);   // 4456448 us
  unsigned short* charinL = (unsigned short*)(base + 95772672);   // 4456448 us
  unsigned short* hc0H = (unsigned short*)(base + 104685568);     // 8388608 us
  unsigned short* hc0L = (unsigned short*)(base + 121462784);     // 8388608 us (X ends 138240000)
  float* dec_out = (float*)(base + 86859776);                     // 8388608 fl (overlay)
  unsigned short* hdecH = (unsigned short*)(base + 120414208);    // 65536 us
  unsigned short* hdecL = (unsigned short*)(base + 120545280);    // 65536 us
  float* c_dec = (float*)(base + 120676352);                      // 32768 fl
  float* clsWT = (float*)(base + 120807424);                      // 15360 fl
  int* cnt = (int*)(base + 120868864);                            // 1024 int (2-level barrier)

  float* dout = (float*)d_out;
  float* diac = dout;              // 8192 x 15
  float* attnmap = dout + 122880;  // 32 x 16 x 16 x 16

  // ---- weight preprocessing (sentence + attention) --------------------------
  transpose_k<<<dim3(32, 8), 256, 0, stream>>>(sent_Wh0, WhT0, 1024, 256, 0);
  transpose_k<<<dim3(32, 8), 256, 0, stream>>>(sent_Wh0 + 262144, WhT0 + 262144, 1024, 256, 0);
  transpose_k<<<dim3(32, 8), 256, 0, stream>>>(sent_Wh1, WhT1, 1024, 256, 0);
  transpose_k<<<dim3(32, 8), 256, 0, stream>>>(sent_Wh1 + 262144, WhT1 + 262144, 1024, 256, 0);
  transpose_k<<<dim3(32, 16), 256, 0, stream>>>(attn_Wq, WqT, 1024, 512, 0);

  // ---- sentence encoder -----------------------------------------------------
  embed_k<<<600, 256, 0, stream>>>(sents, word_embs, wembs);
  gemm_k<1><<<dim3(8, 32), 256, 0, stream>>>(wembs, 300, sent_Wx0, sent_b0,
                                             preS, 2048, 512, 2048, 300);
  sent_rec_k<<<64, 256, 0, stream>>>(preS, WhT0, hs0);
  gemm_k<1><<<dim3(8, 32), 256, 0, stream>>>(hs0, 512, sent_Wx1, sent_b1,
                                             preS, 2048, 512, 2048, 512);
  sent_rec_k<<<64, 256, 0, stream>>>(preS, WhT1, sentenc);

  // ---- char encoder ---------------------------------------------------------
  charin_k<<<17408, 256, 0, stream>>>(words, char_table, sentenc, charinH, charinL);

  hipMemsetAsync(base + 11100160, 0, 6291456, stream);  // hcharH/L + cchar
  for (int s = 0; s < 16; s++) {
    int p = s & 1;
    mstep_k<544><<<dim3(8, 64), 256, 0, stream>>>(
        charinH + s * 544, charinL + s * 544,
        charinH + (15 - s) * 544, charinL + (15 - s) * 544, 16 * 544,
        word_Wx0, word_Wh0, word_b0,
        hcharH + p * 524288, hcharL + p * 524288,
        hcharH + (p ^ 1) * 524288, hcharL + (p ^ 1) * 524288, cchar,
        hc0H, hc0L, 1024, s, 15 - s);
  }
  hipMemsetAsync(base + 11100160, 0, 6291456, stream);
  for (int s = 0; s < 16; s++) {
    int p = s & 1;
    mstep_k<1024><<<dim3(8, 64), 256, 0, stream>>>(
        hc0H + s * 1024, hc0L + s * 1024,
        hc0H + (15 - s) * 1024, hc0L + (15 - s) * 1024, 16 * 1024,
        word_Wx1, word_Wh1, word_b1,
        hcharH + p * 524288, hcharL + p * 524288,
        hcharH + (p ^ 1) * 524288, hcharL + (p ^ 1) * 524288, cchar,
        finalbH + 512, finalbL + 512, 1544, s, 15 - s);
  }

  // ---- attention ------------------------------------------------------------
  mgemm_k<0, 0, 0><<<dim3(128, 8), 256, 0, stream>>>(finalbH + 512, finalbL + 512, 1544, 0,
                                                     WqT, nullptr, qbuf, 512, 1024);
  attn_k<<<512, 256, 0, stream>>>(sentenc, qbuf, words, attnmap, finalbH, finalbL);
  labels_k<<<256, 256, 0, stream>>>(labels, finalbH, finalbL);

  // ---- decoder --------------------------------------------------------------
  decwh_prep_k<<<16384, 256, 0, stream>>>(dec_Wh, WhFH, WhFL);  // overlays Slot Z
  hipMemsetAsync(base + 120414208, 0, 393216, stream);          // hdecH/L + c_dec
  for (int ch = 0; ch < 8; ch++) {
    mgemm_k<1, 1024, 1><<<dim3(16, 64), 256, 0, stream>>>(finalbH, finalbL, 1544, ch * 32,
                                                          dec_Wx, dec_b, pre, 4096, 1544);
    hipMemsetAsync(cnt, 0, 4096, stream);
    dec_persist_k<<<128, 256, 0, stream>>>(WhFH, WhFL, pre, hdecH, hdecL,
                                           c_dec, dec_out, cnt, ch * 32);
  }

  // ---- classifier -----------------------------------------------------------
  transpose_k<<<dim3(32, 1), 256, 0, stream>>>(cls_W, clsWT, 1024, 15, 0);
  gemm_k<1><<<dim3(128, 1), 256, 0, stream>>>(dec_out, 1024, clsWT, cls_b,
                                              diac, 15, 8192, 15, 1024);
}